// Round 4
// baseline (97.869 us; speedup 1.0000x reference)
//
#include <hip/hip_runtime.h>
#include <hip/hip_bf16.h>
#include <hip/hip_fp16.h>

// ---------------- constants (problem is fixed-shape) ----------------
#define SEQ   2048
#define DIM   1024
#define NHEAD 16
#define HD    64
// grid (8,16,16), window (3,5,5) -> half windows 1,2,2
#define QSCALE 0.18033688011112042f   // (1/sqrt(64)) * log2(e), folded into Q

typedef _Float16 half8 __attribute__((ext_vector_type(8)));
typedef _Float16 half4 __attribute__((ext_vector_type(4)));
typedef float    floatx4 __attribute__((ext_vector_type(4)));

// async global->LDS, 16B per lane; LDS dest is wave-uniform base + lane*16,
// global src is PER-LANE -> we use it to stage fragment-ordered (conflict-free) LDS.
__device__ __forceinline__ void gload16(const void* g, void* l) {
    __builtin_amdgcn_global_load_lds(
        (const __attribute__((address_space(1))) unsigned int*)g,
        (__attribute__((address_space(3))) unsigned int*)l, 16, 0, 0);
}

// ---------------- 1. convert fp32 -> fp16 (vectorized) ----------------
__global__ void cvt_f32_f16(const float* __restrict__ in, _Float16* __restrict__ out) {
    int i = blockIdx.x * blockDim.x + threadIdx.x;
    int base = i * 4;
    float4 v = *reinterpret_cast<const float4*>(in + base);
    half4 o = { (_Float16)v.x, (_Float16)v.y, (_Float16)v.z, (_Float16)v.w };
    *reinterpret_cast<half4*>(out + base) = o;
}

// ---------------- 2. transpose + convert weights: T[n][k] = W[k][n] ----------------
__global__ void transpose_cvt(const float* __restrict__ W0, const float* __restrict__ W1,
                              const float* __restrict__ W2, const float* __restrict__ W3,
                              _Float16* __restrict__ T) {
    int z = blockIdx.z;
    const float* W = (z == 0) ? W0 : (z == 1) ? W1 : (z == 2) ? W2 : W3;
    _Float16* Tz = T + (size_t)z * (DIM * DIM);
    __shared__ float tile[32][33];
    int bx = blockIdx.x * 32;   // n-dim base
    int by = blockIdx.y * 32;   // k-dim base
    int tx = threadIdx.x, ty = threadIdx.y;
    #pragma unroll
    for (int i = 0; i < 32; i += 8)
        tile[ty + i][tx] = W[(size_t)(by + ty + i) * DIM + bx + tx];
    __syncthreads();
    #pragma unroll
    for (int i = 0; i < 32; i += 8)
        Tz[(size_t)(bx + ty + i) * DIM + by + tx] = (_Float16)tile[tx][ty + i];
}

// ---------------- GEMM core: 128x64 tile, BK=64, dbuf 2-phase, fragment-ordered LDS ---
// A_tile, B_tile row-major, K-stride DIM, K=1024. 256 threads = 4 waves (2x2);
// wave tile 64x32 = 4x2 frags of mfma_f32_16x16x32_f16 (x2 k-steps per BK=64).
//
// LDS is FRAGMENT-ORDERED: chunk c (1KB) holds the 64-lane data of one frag:
//   A chunk c=(wrow*2+ks): lane l <- A[(c>>1)*16 + (l&15)][k0 + (c&1)*32 + (l>>4)*8 ..+8]
// so compute-phase ds_read_b128 is chunkbase + lane*16: linear, ZERO bank conflicts.
// The per-lane global address of global_load_lds does the permutation for free.
#define LDSBUF 24576   // 16KB A (16 chunks) + 8KB B (8 chunks)

__device__ __forceinline__ void gemm_core(const _Float16* __restrict__ Ap,
                                          const _Float16* __restrict__ Bp,
                                          char* lds, floatx4 (&acc)[4][2]) {
    const int tid  = threadIdx.x;
    const int lane = tid & 63;
    const int wid  = tid >> 6;
    const int wr = wid >> 1, wc = wid & 1;

    // per-lane staging source addresses (same formula for A and B)
    const _Float16* aSrc[4];
    #pragma unroll
    for (int i = 0; i < 4; i++) {
        int c = wid * 4 + i;
        aSrc[i] = Ap + (size_t)((c >> 1) * 16 + (lane & 15)) * DIM + (c & 1) * 32 + (lane >> 4) * 8;
    }
    const _Float16* bSrc[2];
    #pragma unroll
    for (int j = 0; j < 2; j++) {
        int c = wid * 2 + j;
        bSrc[j] = Bp + (size_t)((c >> 1) * 16 + (lane & 15)) * DIM + (c & 1) * 32 + (lane >> 4) * 8;
    }

    auto stage = [&](int buf, int k0) {
        char* Ad = lds + buf * LDSBUF;
        char* Bd = Ad + 16384;
        #pragma unroll
        for (int i = 0; i < 4; i++) gload16(aSrc[i] + k0, Ad + (wid * 4 + i) * 1024);
        #pragma unroll
        for (int j = 0; j < 2; j++) gload16(bSrc[j] + k0, Bd + (wid * 2 + j) * 1024);
    };

    auto compute = [&](int buf) {
        char* Ad = lds + buf * LDSBUF;
        char* Bd = Ad + 16384;
        half8 bf[2][2];
        #pragma unroll
        for (int n = 0; n < 2; n++)
            #pragma unroll
            for (int ks = 0; ks < 2; ks++)
                bf[n][ks] = *reinterpret_cast<half8*>(Bd + ((wc * 2 + n) * 2 + ks) * 1024 + lane * 16);
        #pragma unroll
        for (int m = 0; m < 4; m++)
            #pragma unroll
            for (int ks = 0; ks < 2; ks++) {
                half8 af = *reinterpret_cast<half8*>(Ad + ((wr * 4 + m) * 2 + ks) * 1024 + lane * 16);
                #pragma unroll
                for (int n = 0; n < 2; n++)
                    acc[m][n] = __builtin_amdgcn_mfma_f32_16x16x32_f16(af, bf[n][ks], acc[m][n], 0, 0, 0);
            }
    };

    stage(0, 0);
    __syncthreads();                       // drains vmcnt -> buf0 ready
    #pragma unroll 1
    for (int t = 0; t < 16; t += 2) {      // 16 K-steps of 64
        stage(1, (t + 1) * 64);            // issue BEFORE compute: latency hides under MFMA
        compute(0);
        __syncthreads();                   // vmcnt(0)+lgkmcnt(0)+barrier: buf1 ready, buf0 free
        if (t + 2 < 16) stage(0, (t + 2) * 64);
        compute(1);
        __syncthreads();
    }
}

// ---------------- 3. fused QKV projections ----------------
// z=0: Q = H*Wq^T (scaled, per-head layout)  z=1: K (per-head layout)
// z=2: V^T = Wv^T * H^T (row-major [1024][2048]), tiles remapped from the 16x16 grid
__global__ __launch_bounds__(256) void gemm_qkv(
        const _Float16* __restrict__ Hf, const _Float16* __restrict__ Wt,
        _Float16* __restrict__ Qp, _Float16* __restrict__ Kp, _Float16* __restrict__ Vt) {
    __shared__ char lds[2 * LDSBUF];
    floatx4 acc[4][2] = {};

    int z = blockIdx.z;
    int tm, tn;
    const _Float16 *Ap, *Bp;
    if (z < 2) {
        tm = blockIdx.x; tn = blockIdx.y;                      // 16 x 16
        Ap = Hf + (size_t)tm * 128 * DIM;
        Bp = Wt + (size_t)z * DIM * DIM + (size_t)tn * 64 * DIM;
    } else {
        tm = blockIdx.x & 7; tn = blockIdx.y * 2 + (blockIdx.x >> 3);  // 8 x 32
        Ap = Wt + (size_t)2 * DIM * DIM + (size_t)tm * 128 * DIM;
        Bp = Hf + (size_t)tn * 64 * DIM;
    }
    gemm_core(Ap, Bp, lds, acc);

    int lane = threadIdx.x & 63, wid = threadIdx.x >> 6;
    int wr = wid >> 1, wc = wid & 1;
    float qs = (z == 0) ? QSCALE : 1.0f;
    _Float16* Oz = (z == 0) ? Qp : Kp;

    #pragma unroll
    for (int m = 0; m < 4; m++) {
        #pragma unroll
        for (int n = 0; n < 2; n++) {
            #pragma unroll
            for (int r = 0; r < 4; r++) {
                int row = tm * 128 + wr * 64 + m * 16 + (lane >> 4) * 4 + r;
                int col = tn * 64 + wc * 32 + n * 16 + (lane & 15);
                float v = acc[m][n][r];
                if (z < 2) {
                    int head = col >> 6;
                    Oz[(size_t)head * (SEQ * HD) + (size_t)row * HD + (col & 63)] = (_Float16)(v * qs);
                } else {
                    Vt[(size_t)row * SEQ + col] = (_Float16)v;
                }
            }
        }
    }
}

// ---------------- 5. output projection + bias ----------------
__global__ __launch_bounds__(256) void gemm_o(
        const _Float16* __restrict__ AO, const _Float16* __restrict__ WoT,
        const float* __restrict__ bias, float* __restrict__ out) {
    __shared__ char lds[2 * LDSBUF];
    floatx4 acc[4][2] = {};

    int tm = blockIdx.x, tn = blockIdx.y;                      // 16 x 16
    gemm_core(AO + (size_t)tm * 128 * DIM, WoT + (size_t)tn * 64 * DIM, lds, acc);

    int lane = threadIdx.x & 63, wid = threadIdx.x >> 6;
    int wr = wid >> 1, wc = wid & 1;
    #pragma unroll
    for (int m = 0; m < 4; m++) {
        #pragma unroll
        for (int n = 0; n < 2; n++) {
            #pragma unroll
            for (int r = 0; r < 4; r++) {
                int row = tm * 128 + wr * 64 + m * 16 + (lane >> 4) * 4 + r;
                int col = tn * 64 + wc * 32 + n * 16 + (lane & 15);
                out[(size_t)row * DIM + col] = acc[m][n][r] + bias[col];
            }
        }
    }
}

// ---------------- 4. MFMA windowed attention: 1 wave per (head, f, h) row ----------------
// 16 queries (one w-row). Keys: 3 f-chunks x 6 h-rows x 16 w = 288, contiguous per chunk.
// Q pre-scaled by QSCALE at GEMM; softmax = exp2 with no max-sub; normalize at epilogue.
__global__ __launch_bounds__(256) void attn_mfma(
        const _Float16* __restrict__ Q,    // [16][2048][64] (scaled)
        const _Float16* __restrict__ K,    // [16][2048][64]
        const _Float16* __restrict__ Vt,   // [16][64][2048]
        _Float16* __restrict__ AO) {       // [2048][1024]
    __shared__ char P_lds[4][16 * 640];    // per-wave P[16 q][288 key] f16, XOR-swizzled

    int wid  = threadIdx.x >> 6;
    int lane = threadIdx.x & 63;
    int g    = lane >> 4;      // 0..3
    int ql   = lane & 15;

    int bid  = blockIdx.x * 4 + wid;
    int rid  = bid & 127;      // (f,h)
    int head = bid >> 7;
    int f    = rid >> 4;
    int hq   = rid & 15;
    int s0   = rid << 4;

    const _Float16* Qh = Q  + (size_t)head * (SEQ * HD);
    const _Float16* Kh = K  + (size_t)head * (SEQ * HD);
    const _Float16* Vh = Vt + (size_t)head * (HD * SEQ);

    int f_start = min(max(f - 1, 0), 5);
    int h_start = min(max(hq - 2, 0), 10);

    // per-lane w-mask: key w' = g*4+r, query w = ql
    bool wm[4];
    #pragma unroll
    for (int r = 0; r < 4; r++) {
        int wp = g * 4 + r;
        wm[r] = (wp - ql <= 2) && (ql - wp <= 2);
    }

    // Q B-frags (2 k-steps over d=64)
    half8 qf[2];
    #pragma unroll
    for (int ks = 0; ks < 2; ks++)
        qf[ks] = *reinterpret_cast<const half8*>(Qh + (size_t)(s0 + ql) * HD + ks * 32 + g * 8);

    float lsum = 0.f;
    int swz = (ql & 7) << 4;

    #pragma unroll
    for (int fi = 0; fi < 3; fi++) {
        int fp = f_start + fi;
        bool fok = (fp - f <= 1) && (f - fp <= 1);
        int sbase = fp * 256 + h_start * 16;
        const _Float16* Kc = Kh + (size_t)sbase * HD;

        floatx4 sacc[6];
        #pragma unroll
        for (int j = 0; j < 6; j++) sacc[j] = (floatx4){0.f, 0.f, 0.f, 0.f};

        #pragma unroll
        for (int j = 0; j < 6; j++) {
            #pragma unroll
            for (int ks = 0; ks < 2; ks++) {
                half8 kf = *reinterpret_cast<const half8*>(Kc + (size_t)(j * 16 + ql) * HD + ks * 32 + g * 8);
                sacc[j] = __builtin_amdgcn_mfma_f32_16x16x32_f16(kf, qf[ks], sacc[j], 0, 0, 0);
            }
        }

        #pragma unroll
        for (int j = 0; j < 6; j++) {
            int hp = h_start + j;
            bool ok = fok && (hp - hq <= 2) && (hq - hp <= 2);
            half4 pv;
            #pragma unroll
            for (int r = 0; r < 4; r++) {
                float sv = (ok && wm[r]) ? sacc[j][r] : -10000.f;
                float p  = __builtin_amdgcn_exp2f(sv);
                lsum += p;
                pv[r] = (_Float16)p;
            }
            int byte = (ql * 640 + (fi * 96 + j * 16 + g * 4) * 2) ^ swz;
            *reinterpret_cast<half4*>(&P_lds[wid][byte]) = pv;
        }
    }

    // row sums (q = ql lives in 4 lane-groups)
    lsum += __shfl_xor(lsum, 16);
    lsum += __shfl_xor(lsum, 32);
    float inv = __builtin_amdgcn_rcpf(lsum);

    __syncthreads();

    floatx4 oacc[4];
    #pragma unroll
    for (int dt = 0; dt < 4; dt++) oacc[dt] = (floatx4){0.f, 0.f, 0.f, 0.f};

    #pragma unroll
    for (int fi = 0; fi < 3; fi++) {
        int sbase = (f_start + fi) * 256 + h_start * 16;
        #pragma unroll
        for (int kw = 0; kw < 3; kw++) {
            int kcol = fi * 96 + kw * 32;
            int byte = (ql * 640 + (kcol + g * 8) * 2) ^ swz;
            half8 pa = *reinterpret_cast<half8*>(&P_lds[wid][byte]);
            #pragma unroll
            for (int dt = 0; dt < 4; dt++) {
                half8 vf = *reinterpret_cast<const half8*>(
                    Vh + (size_t)(dt * 16 + ql) * SEQ + sbase + kw * 32 + g * 8);
                oacc[dt] = __builtin_amdgcn_mfma_f32_16x16x32_f16(pa, vf, oacc[dt], 0, 0, 0);
            }
        }
    }

    // epilogue: C row = q = g*4+rr, col = d = dt*16+ql; scale by 1/sum
    #pragma unroll
    for (int rr = 0; rr < 4; rr++) {
        float invr = __shfl(inv, g * 4 + rr);
        #pragma unroll
        for (int dt = 0; dt < 4; dt++) {
            AO[(size_t)(s0 + g * 4 + rr) * DIM + head * HD + dt * 16 + ql] =
                (_Float16)(oacc[dt][rr] * invr);
        }
    }
}

// ---------------- launch ----------------
extern "C" void kernel_launch(void* const* d_in, const int* in_sizes, int n_in,
                              void* d_out, int out_size, void* d_ws, size_t ws_size,
                              hipStream_t stream) {
    const float* H  = (const float*)d_in[0];
    const float* Wq = (const float*)d_in[1];
    const float* Wk = (const float*)d_in[2];
    const float* Wv = (const float*)d_in[3];
    const float* Wo = (const float*)d_in[4];
    const float* bo = (const float*)d_in[5];

    char* ws = (char*)d_ws;
    // layout: Hf16 [0,4M) | Wt x4 [4M,12M) | Q [12M,16M) | K [16M,20M) | Vt [20M,24M) | AO [24M,28M)
    _Float16* Hf = (_Float16*)(ws);
    _Float16* Wt = (_Float16*)(ws + (4u  << 20));
    _Float16* Qp = (_Float16*)(ws + (12u << 20));
    _Float16* Kp = (_Float16*)(ws + (16u << 20));
    _Float16* Vt = (_Float16*)(ws + (20u << 20));
    _Float16* AO = (_Float16*)(ws + (24u << 20));

    // 1. H -> f16
    cvt_f32_f16<<<(SEQ * DIM) / (256 * 4), 256, 0, stream>>>(H, Hf);

    // 2. weights -> transposed f16 (Wt[z][n][k] = W[k][n])
    transpose_cvt<<<dim3(32, 32, 4), dim3(32, 8), 0, stream>>>(Wq, Wk, Wv, Wo, Wt);

    // 3. fused Q, K, V^T projections: 768 WGs = exactly 3/CU
    gemm_qkv<<<dim3(16, 16, 3), 256, 0, stream>>>(Hf, Wt, Qp, Kp, Vt);

    // 4. windowed MFMA attention: 2048 one-wave rows, 4 per block
    attn_mfma<<<dim3(NHEAD * 128 / 4), 256, 0, stream>>>(Qp, Kp, Vt, AO);

    // 5. output projection + bias: 256 WGs = 1/CU (was 128 = half idle)
    gemm_o<<<dim3(16, 16), 256, 0, stream>>>(AO, Wt + (size_t)3 * DIM * DIM, bo, (float*)d_out);
}

// Round 5
// 84.199 us; speedup vs baseline: 1.1624x; 1.1624x over previous
//
#include <hip/hip_runtime.h>
#include <hip/hip_bf16.h>
#include <hip/hip_fp16.h>

// ---------------- constants (problem is fixed-shape) ----------------
#define SEQ   2048
#define DIM   1024
#define NHEAD 16
#define HD    64
// grid (8,16,16), window (3,5,5) -> half windows 1,2,2
#define QSCALE 0.18033688011112042f   // (1/sqrt(64)) * log2(e), folded into Q

typedef _Float16 half8 __attribute__((ext_vector_type(8)));
typedef _Float16 half4 __attribute__((ext_vector_type(4)));
typedef float    floatx4 __attribute__((ext_vector_type(4)));

// async global->LDS, 16B per lane; LDS dest is wave-uniform base + lane*16
__device__ __forceinline__ void gload16(const void* g, void* l) {
    __builtin_amdgcn_global_load_lds(
        (const __attribute__((address_space(1))) unsigned int*)g,
        (__attribute__((address_space(3))) unsigned int*)l, 16, 0, 0);
}

// ---------------- 1+2 merged prep: weight transpose-cvt (z 0..3) + H cvt (z 4) ----
__global__ __launch_bounds__(256) void prep(
        const float* __restrict__ H, _Float16* __restrict__ Hf,
        const float* __restrict__ W0, const float* __restrict__ W1,
        const float* __restrict__ W2, const float* __restrict__ W3,
        _Float16* __restrict__ T) {
    __shared__ float tile[32][33];
    int z = blockIdx.z;
    int tx = threadIdx.x, ty = threadIdx.y;
    if (z < 4) {
        const float* W = (z == 0) ? W0 : (z == 1) ? W1 : (z == 2) ? W2 : W3;
        _Float16* Tz = T + (size_t)z * (DIM * DIM);
        int bx = blockIdx.x * 32;   // n-dim base
        int by = blockIdx.y * 32;   // k-dim base
        #pragma unroll
        for (int i = 0; i < 32; i += 8)
            tile[ty + i][tx] = W[(size_t)(by + ty + i) * DIM + bx + tx];
        __syncthreads();
        #pragma unroll
        for (int i = 0; i < 32; i += 8)
            Tz[(size_t)(bx + ty + i) * DIM + by + tx] = (_Float16)tile[tx][ty + i];
    } else {
        // convert H (2M floats): 1024 WGs x 256 threads x 8 elems
        int wg = blockIdx.y * 32 + blockIdx.x;
        int lt = ty * 32 + tx;
        int base = (wg * 256 + lt) * 8;
        float4 v0 = *reinterpret_cast<const float4*>(H + base);
        float4 v1 = *reinterpret_cast<const float4*>(H + base + 4);
        half8 o = { (_Float16)v0.x, (_Float16)v0.y, (_Float16)v0.z, (_Float16)v0.w,
                    (_Float16)v1.x, (_Float16)v1.y, (_Float16)v1.z, (_Float16)v1.w };
        *reinterpret_cast<half8*>(Hf + base) = o;
    }
}

// ---------------- GEMM core: 128x128 tile, BK=64, single-buffer ----------------
// A_tile, B_tile row-major, K-stride DIM, K=1024. 256 threads = 4 waves (2x2);
// wave = 64x64 = 4x4 frags of mfma_f32_16x16x32_f16, x2 k-subtiles per BK=64.
// LDS: A as two [128][32] ks-halves (16KB), B same (16KB) -> 32KB total.
// Stage instr i (i&1 -> +64 rows, i>>1 -> ks half); per-wave dest linear, so the
// frag read (16 rows x 64B = 1KB contiguous per fragment set) stays conflict-free.
__device__ __forceinline__ void gemm_core(const _Float16* __restrict__ Ap,
                                          const _Float16* __restrict__ Bp,
                                          char* lds, floatx4 (&acc)[4][4]) {
    const int tid  = threadIdx.x;
    const int lane = tid & 63;
    const int wid  = tid >> 6;
    const int wr = wid >> 1, wc = wid & 1;
    const int r16 = lane & 15;
    const int kk  = (lane >> 4) * 8;

    const int srow = tid >> 2, scol = (tid & 3) * 8;
    const _Float16* As0 = Ap + (size_t)srow * DIM + scol;
    const _Float16* Bs0 = Bp + (size_t)srow * DIM + scol;
    char* Alds = lds;
    char* Blds = lds + 16384;

    for (int k0 = 0; k0 < DIM; k0 += 64) {
        #pragma unroll
        for (int i = 0; i < 4; i++) {
            int off = (i & 1) * 64 * DIM + (i >> 1) * 32 + k0;
            gload16(As0 + off, Alds + i * 4096 + wid * 1024);
            gload16(Bs0 + off, Blds + i * 4096 + wid * 1024);
        }
        __syncthreads();                 // vmcnt(0): buffer ready
        #pragma unroll
        for (int ks = 0; ks < 2; ks++) {
            half8 a[4], b[4];
            #pragma unroll
            for (int m = 0; m < 4; m++)
                a[m] = *reinterpret_cast<half8*>(Alds + ks * 8192 + (wr * 64 + m * 16 + r16) * 64 + kk * 2);
            #pragma unroll
            for (int n = 0; n < 4; n++)
                b[n] = *reinterpret_cast<half8*>(Blds + ks * 8192 + (wc * 64 + n * 16 + r16) * 64 + kk * 2);
            #pragma unroll
            for (int m = 0; m < 4; m++)
                #pragma unroll
                for (int n = 0; n < 4; n++)
                    acc[m][n] = __builtin_amdgcn_mfma_f32_16x16x32_f16(a[m], b[n], acc[m][n], 0, 0, 0);
        }
        __syncthreads();                 // protect overwrite
    }
}

// ---------------- 3. fused QKV projections ----------------
// z=0: Q = H*Wq^T (scaled, per-head layout)  z=1: K (per-head layout)
// z=2: V^T = Wv^T * H^T  (row-major [1024][2048]), tiles remapped from 16x8 grid
__global__ __launch_bounds__(256) void gemm_qkv(
        const _Float16* __restrict__ Hf, const _Float16* __restrict__ Wt,
        _Float16* __restrict__ Qp, _Float16* __restrict__ Kp, _Float16* __restrict__ Vt) {
    __shared__ char lds[32768];
    floatx4 acc[4][4] = {};

    int z = blockIdx.z;
    int tm, tn;
    const _Float16 *Ap, *Bp;
    if (z < 2) {
        tm = blockIdx.x; tn = blockIdx.y;                      // 16 x 8
        Ap = Hf + (size_t)tm * 128 * DIM;
        Bp = Wt + (size_t)z * DIM * DIM + (size_t)tn * 128 * DIM;
    } else {
        tm = blockIdx.x & 7; tn = blockIdx.y * 2 + (blockIdx.x >> 3);  // 8 x 16
        Ap = Wt + (size_t)2 * DIM * DIM + (size_t)tm * 128 * DIM;
        Bp = Hf + (size_t)tn * 128 * DIM;
    }
    gemm_core(Ap, Bp, lds, acc);

    int lane = threadIdx.x & 63, wid = threadIdx.x >> 6;
    int wr = wid >> 1, wc = wid & 1;
    float qs = (z == 0) ? QSCALE : 1.0f;
    _Float16* Oz = (z == 0) ? Qp : Kp;

    #pragma unroll
    for (int m = 0; m < 4; m++) {
        #pragma unroll
        for (int n = 0; n < 4; n++) {
            #pragma unroll
            for (int r = 0; r < 4; r++) {
                int row = tm * 128 + wr * 64 + m * 16 + (lane >> 4) * 4 + r;
                int col = tn * 128 + wc * 64 + n * 16 + (lane & 15);
                float v = acc[m][n][r];
                if (z < 2) {
                    int head = col >> 6;
                    Oz[(size_t)head * (SEQ * HD) + (size_t)row * HD + (col & 63)] = (_Float16)(v * qs);
                } else {
                    Vt[(size_t)row * SEQ + col] = (_Float16)v;
                }
            }
        }
    }
}

// ---------------- 5. output projection + bias ----------------
__global__ __launch_bounds__(256) void gemm_o(
        const _Float16* __restrict__ AO, const _Float16* __restrict__ WoT,
        const float* __restrict__ bias, float* __restrict__ out) {
    __shared__ char lds[32768];
    floatx4 acc[4][4] = {};

    int tm = blockIdx.x, tn = blockIdx.y;                      // 16 x 8
    gemm_core(AO + (size_t)tm * 128 * DIM, WoT + (size_t)tn * 128 * DIM, lds, acc);

    int lane = threadIdx.x & 63, wid = threadIdx.x >> 6;
    int wr = wid >> 1, wc = wid & 1;
    #pragma unroll
    for (int m = 0; m < 4; m++) {
        #pragma unroll
        for (int n = 0; n < 4; n++) {
            #pragma unroll
            for (int r = 0; r < 4; r++) {
                int row = tm * 128 + wr * 64 + m * 16 + (lane >> 4) * 4 + r;
                int col = tn * 128 + wc * 64 + n * 16 + (lane & 15);
                out[(size_t)row * DIM + col] = acc[m][n][r] + bias[col];
            }
        }
    }
}

// ---------------- 4. MFMA windowed attention: 1 wave per (head, f, h) row ----------------
// 16 queries (one w-row). Keys: 3 f-chunks x 6 h-rows x 16 w = 288, contiguous per chunk.
// Q pre-scaled by QSCALE at GEMM; softmax = exp2 with no max-sub; normalize at epilogue.
__global__ __launch_bounds__(256) void attn_mfma(
        const _Float16* __restrict__ Q,    // [16][2048][64] (scaled)
        const _Float16* __restrict__ K,    // [16][2048][64]
        const _Float16* __restrict__ Vt,   // [16][64][2048]
        _Float16* __restrict__ AO) {       // [2048][1024]
    __shared__ char P_lds[4][16 * 640];    // per-wave P[16 q][288 key] f16, XOR-swizzled

    int wid  = threadIdx.x >> 6;
    int lane = threadIdx.x & 63;
    int g    = lane >> 4;      // 0..3
    int ql   = lane & 15;

    int bid  = blockIdx.x * 4 + wid;
    int rid  = bid & 127;      // (f,h)
    int head = bid >> 7;
    int f    = rid >> 4;
    int hq   = rid & 15;
    int s0   = rid << 4;

    const _Float16* Qh = Q  + (size_t)head * (SEQ * HD);
    const _Float16* Kh = K  + (size_t)head * (SEQ * HD);
    const _Float16* Vh = Vt + (size_t)head * (HD * SEQ);

    int f_start = min(max(f - 1, 0), 5);
    int h_start = min(max(hq - 2, 0), 10);

    // per-lane w-mask: key w' = g*4+r, query w = ql
    bool wm[4];
    #pragma unroll
    for (int r = 0; r < 4; r++) {
        int wp = g * 4 + r;
        wm[r] = (wp - ql <= 2) && (ql - wp <= 2);
    }

    // Q B-frags (2 k-steps over d=64)
    half8 qf[2];
    #pragma unroll
    for (int ks = 0; ks < 2; ks++)
        qf[ks] = *reinterpret_cast<const half8*>(Qh + (size_t)(s0 + ql) * HD + ks * 32 + g * 8);

    float lsum = 0.f;
    int swz = (ql & 7) << 4;

    #pragma unroll
    for (int fi = 0; fi < 3; fi++) {
        int fp = f_start + fi;
        bool fok = (fp - f <= 1) && (f - fp <= 1);
        int sbase = fp * 256 + h_start * 16;
        const _Float16* Kc = Kh + (size_t)sbase * HD;

        floatx4 sacc[6];
        #pragma unroll
        for (int j = 0; j < 6; j++) sacc[j] = (floatx4){0.f, 0.f, 0.f, 0.f};

        #pragma unroll
        for (int j = 0; j < 6; j++) {
            #pragma unroll
            for (int ks = 0; ks < 2; ks++) {
                half8 kf = *reinterpret_cast<const half8*>(Kc + (size_t)(j * 16 + ql) * HD + ks * 32 + g * 8);
                sacc[j] = __builtin_amdgcn_mfma_f32_16x16x32_f16(kf, qf[ks], sacc[j], 0, 0, 0);
            }
        }

        #pragma unroll
        for (int j = 0; j < 6; j++) {
            int hp = h_start + j;
            bool ok = fok && (hp - hq <= 2) && (hq - hp <= 2);
            half4 pv;
            #pragma unroll
            for (int r = 0; r < 4; r++) {
                float sv = (ok && wm[r]) ? sacc[j][r] : -10000.f;
                float p  = __builtin_amdgcn_exp2f(sv);
                lsum += p;
                pv[r] = (_Float16)p;
            }
            int byte = (ql * 640 + (fi * 96 + j * 16 + g * 4) * 2) ^ swz;
            *reinterpret_cast<half4*>(&P_lds[wid][byte]) = pv;
        }
    }

    // row sums (q = ql lives in 4 lane-groups)
    lsum += __shfl_xor(lsum, 16);
    lsum += __shfl_xor(lsum, 32);
    float inv = __builtin_amdgcn_rcpf(lsum);

    __syncthreads();

    floatx4 oacc[4];
    #pragma unroll
    for (int dt = 0; dt < 4; dt++) oacc[dt] = (floatx4){0.f, 0.f, 0.f, 0.f};

    #pragma unroll
    for (int fi = 0; fi < 3; fi++) {
        int sbase = (f_start + fi) * 256 + h_start * 16;
        #pragma unroll
        for (int kw = 0; kw < 3; kw++) {
            int kcol = fi * 96 + kw * 32;
            int byte = (ql * 640 + (kcol + g * 8) * 2) ^ swz;
            half8 pa = *reinterpret_cast<half8*>(&P_lds[wid][byte]);
            #pragma unroll
            for (int dt = 0; dt < 4; dt++) {
                half8 vf = *reinterpret_cast<const half8*>(
                    Vh + (size_t)(dt * 16 + ql) * SEQ + sbase + kw * 32 + g * 8);
                oacc[dt] = __builtin_amdgcn_mfma_f32_16x16x32_f16(pa, vf, oacc[dt], 0, 0, 0);
            }
        }
    }

    // epilogue: C row = q = g*4+rr, col = d = dt*16+ql; scale by 1/sum
    #pragma unroll
    for (int rr = 0; rr < 4; rr++) {
        float invr = __shfl(inv, g * 4 + rr);
        #pragma unroll
        for (int dt = 0; dt < 4; dt++) {
            AO[(size_t)(s0 + g * 4 + rr) * DIM + head * HD + dt * 16 + ql] =
                (_Float16)(oacc[dt][rr] * invr);
        }
    }
}

// ---------------- launch ----------------
extern "C" void kernel_launch(void* const* d_in, const int* in_sizes, int n_in,
                              void* d_out, int out_size, void* d_ws, size_t ws_size,
                              hipStream_t stream) {
    const float* H  = (const float*)d_in[0];
    const float* Wq = (const float*)d_in[1];
    const float* Wk = (const float*)d_in[2];
    const float* Wv = (const float*)d_in[3];
    const float* Wo = (const float*)d_in[4];
    const float* bo = (const float*)d_in[5];

    char* ws = (char*)d_ws;
    // layout: Hf16 [0,4M) | Wt x4 [4M,12M) | Q [12M,16M) | K [16M,20M) | Vt [20M,24M) | AO [24M,28M)
    _Float16* Hf = (_Float16*)(ws);
    _Float16* Wt = (_Float16*)(ws + (4u  << 20));
    _Float16* Qp = (_Float16*)(ws + (12u << 20));
    _Float16* Kp = (_Float16*)(ws + (16u << 20));
    _Float16* Vt = (_Float16*)(ws + (20u << 20));
    _Float16* AO = (_Float16*)(ws + (24u << 20));

    // 1+2. H -> f16 and weights -> transposed f16 (merged)
    prep<<<dim3(32, 32, 5), dim3(32, 8), 0, stream>>>(H, Hf, Wq, Wk, Wv, Wo, Wt);

    // 3. fused Q, K, V^T projections (z=0,1: QK per-head; z=2: V^T remapped)
    gemm_qkv<<<dim3(16, 8, 3), 256, 0, stream>>>(Hf, Wt, Qp, Kp, Vt);

    // 4. windowed MFMA attention: 2048 one-wave rows, 4 per block
    attn_mfma<<<dim3(NHEAD * 128 / 4), 256, 0, stream>>>(Qp, Kp, Vt, AO);

    // 5. output projection + bias
    gemm_o<<<dim3(16, 8), 256, 0, stream>>>(AO, Wt + (size_t)3 * DIM * DIM, bo, (float*)d_out);
}

// Round 6
// 80.855 us; speedup vs baseline: 1.2104x; 1.0414x over previous
//
#include <hip/hip_runtime.h>
#include <hip/hip_bf16.h>
#include <hip/hip_fp16.h>

// ---------------- constants (problem is fixed-shape) ----------------
#define SEQ   2048
#define DIM   1024
#define NHEAD 16
#define HD    64
// grid (8,16,16), window (3,5,5) -> half windows 1,2,2
#define QSCALE 0.18033688011112042f   // (1/sqrt(64)) * log2(e), folded into Q

typedef _Float16 half8 __attribute__((ext_vector_type(8)));
typedef _Float16 half4 __attribute__((ext_vector_type(4)));
typedef float    floatx4 __attribute__((ext_vector_type(4)));

// async global->LDS, 16B per lane; LDS dest is wave-uniform base + lane*16
__device__ __forceinline__ void gload16(const void* g, void* l) {
    __builtin_amdgcn_global_load_lds(
        (const __attribute__((address_space(1))) unsigned int*)g,
        (__attribute__((address_space(3))) unsigned int*)l, 16, 0, 0);
}

// ---------------- 1+2 merged prep: weight transpose-cvt (z 0..3) + H cvt (z 4) ----
__global__ __launch_bounds__(256) void prep(
        const float* __restrict__ H, _Float16* __restrict__ Hf,
        const float* __restrict__ W0, const float* __restrict__ W1,
        const float* __restrict__ W2, const float* __restrict__ W3,
        _Float16* __restrict__ T) {
    __shared__ float tile[32][33];
    int z = blockIdx.z;
    int tx = threadIdx.x, ty = threadIdx.y;
    if (z < 4) {
        const float* W = (z == 0) ? W0 : (z == 1) ? W1 : (z == 2) ? W2 : W3;
        _Float16* Tz = T + (size_t)z * (DIM * DIM);
        int bx = blockIdx.x * 32;   // n-dim base
        int by = blockIdx.y * 32;   // k-dim base
        #pragma unroll
        for (int i = 0; i < 32; i += 8)
            tile[ty + i][tx] = W[(size_t)(by + ty + i) * DIM + bx + tx];
        __syncthreads();
        #pragma unroll
        for (int i = 0; i < 32; i += 8)
            Tz[(size_t)(bx + ty + i) * DIM + by + tx] = (_Float16)tile[tx][ty + i];
    } else {
        // convert H (2M floats): 1024 WGs x 256 threads x 8 elems
        int wg = blockIdx.y * 32 + blockIdx.x;
        int lt = ty * 32 + tx;
        int base = (wg * 256 + lt) * 8;
        float4 v0 = *reinterpret_cast<const float4*>(H + base);
        float4 v1 = *reinterpret_cast<const float4*>(H + base + 4);
        half8 o = { (_Float16)v0.x, (_Float16)v0.y, (_Float16)v0.z, (_Float16)v0.w,
                    (_Float16)v1.x, (_Float16)v1.y, (_Float16)v1.z, (_Float16)v1.w };
        *reinterpret_cast<half8*>(Hf + base) = o;
    }
}

// ---------------- GEMM core: 128x128 tile, BK=32, DOUBLE-BUFFERED 2-phase ----------
// A_tile, B_tile row-major, K-stride DIM, K=1024. 256 threads = 4 waves (2x2);
// wave = 64x64 = 4x4 frags of mfma_f32_16x16x32_f16.
// LDS per buffer: A [128][32] f16 (8KB) + B [128][32] (8KB); 2 buffers = 32KB.
// Pipeline: prefetch K-step t+1 BEFORE computing t; ONE barrier per K-step placed
// AFTER compute, so the vmcnt(0) drain overlaps the ds_read+MFMA of step t.
__device__ __forceinline__ void gemm_core(const _Float16* __restrict__ Ap,
                                          const _Float16* __restrict__ Bp,
                                          char* lds, floatx4 (&acc)[4][4]) {
    const int tid  = threadIdx.x;
    const int lane = tid & 63;
    const int wid  = tid >> 6;
    const int wr = wid >> 1, wc = wid & 1;
    const int r16 = lane & 15;
    const int kk  = (lane >> 4) * 8;

    // staging map: LDS byte (i*4096 + tid*16) <-> elem row = i*64 + (tid>>2), col = (tid&3)*8
    const int srow = tid >> 2, scol = (tid & 3) * 8;
    const _Float16* As0 = Ap + (size_t)srow * DIM + scol;
    const _Float16* Bs0 = Bp + (size_t)srow * DIM + scol;

    auto stage = [&](int buf, int k0) {
        char* Ad = lds + buf * 16384;
        char* Bd = Ad + 8192;
        #pragma unroll
        for (int i = 0; i < 2; i++) {
            gload16(As0 + (size_t)i * 64 * DIM + k0, Ad + i * 4096 + wid * 1024);
            gload16(Bs0 + (size_t)i * 64 * DIM + k0, Bd + i * 4096 + wid * 1024);
        }
    };

    auto compute = [&](int buf) {
        char* Ad = lds + buf * 16384;
        char* Bd = Ad + 8192;
        half8 a[4], b[4];
        #pragma unroll
        for (int m = 0; m < 4; m++)
            a[m] = *reinterpret_cast<half8*>(Ad + (wr * 64 + m * 16 + r16) * 64 + kk * 2);
        #pragma unroll
        for (int n = 0; n < 4; n++)
            b[n] = *reinterpret_cast<half8*>(Bd + (wc * 64 + n * 16 + r16) * 64 + kk * 2);
        #pragma unroll
        for (int m = 0; m < 4; m++)
            #pragma unroll
            for (int n = 0; n < 4; n++)
                acc[m][n] = __builtin_amdgcn_mfma_f32_16x16x32_f16(a[m], b[n], acc[m][n], 0, 0, 0);
    };

    stage(0, 0);
    __syncthreads();                       // buf0 ready
    #pragma unroll 1
    for (int t = 0; t < 32; t += 2) {
        stage(1, (t + 1) * 32);            // prefetch issued BEFORE compute
        compute(0);
        __syncthreads();                   // drain: prefetch had compute-time in flight
        if (t + 2 < 32) stage(0, (t + 2) * 32);
        compute(1);
        __syncthreads();
    }
}

// ---------------- 3. fused QKV projections ----------------
// z=0: Q = H*Wq^T (scaled, per-head layout)  z=1: K (per-head layout)
// z=2: V^T = Wv^T * H^T  (row-major [1024][2048]), tiles remapped from 16x8 grid
__global__ __launch_bounds__(256) void gemm_qkv(
        const _Float16* __restrict__ Hf, const _Float16* __restrict__ Wt,
        _Float16* __restrict__ Qp, _Float16* __restrict__ Kp, _Float16* __restrict__ Vt) {
    __shared__ char lds[32768];
    floatx4 acc[4][4] = {};

    int z = blockIdx.z;
    int tm, tn;
    const _Float16 *Ap, *Bp;
    if (z < 2) {
        tm = blockIdx.x; tn = blockIdx.y;                      // 16 x 8
        Ap = Hf + (size_t)tm * 128 * DIM;
        Bp = Wt + (size_t)z * DIM * DIM + (size_t)tn * 128 * DIM;
    } else {
        tm = blockIdx.x & 7; tn = blockIdx.y * 2 + (blockIdx.x >> 3);  // 8 x 16
        Ap = Wt + (size_t)2 * DIM * DIM + (size_t)tm * 128 * DIM;
        Bp = Hf + (size_t)tn * 128 * DIM;
    }
    gemm_core(Ap, Bp, lds, acc);

    int lane = threadIdx.x & 63, wid = threadIdx.x >> 6;
    int wr = wid >> 1, wc = wid & 1;
    float qs = (z == 0) ? QSCALE : 1.0f;
    _Float16* Oz = (z == 0) ? Qp : Kp;

    #pragma unroll
    for (int m = 0; m < 4; m++) {
        #pragma unroll
        for (int n = 0; n < 4; n++) {
            #pragma unroll
            for (int r = 0; r < 4; r++) {
                int row = tm * 128 + wr * 64 + m * 16 + (lane >> 4) * 4 + r;
                int col = tn * 128 + wc * 64 + n * 16 + (lane & 15);
                float v = acc[m][n][r];
                if (z < 2) {
                    int head = col >> 6;
                    Oz[(size_t)head * (SEQ * HD) + (size_t)row * HD + (col & 63)] = (_Float16)(v * qs);
                } else {
                    Vt[(size_t)row * SEQ + col] = (_Float16)v;
                }
            }
        }
    }
}

// ---------------- 5. output projection + bias ----------------
__global__ __launch_bounds__(256) void gemm_o(
        const _Float16* __restrict__ AO, const _Float16* __restrict__ WoT,
        const float* __restrict__ bias, float* __restrict__ out) {
    __shared__ char lds[32768];
    floatx4 acc[4][4] = {};

    int tm = blockIdx.x, tn = blockIdx.y;                      // 16 x 8
    gemm_core(AO + (size_t)tm * 128 * DIM, WoT + (size_t)tn * 128 * DIM, lds, acc);

    int lane = threadIdx.x & 63, wid = threadIdx.x >> 6;
    int wr = wid >> 1, wc = wid & 1;
    #pragma unroll
    for (int m = 0; m < 4; m++) {
        #pragma unroll
        for (int n = 0; n < 4; n++) {
            #pragma unroll
            for (int r = 0; r < 4; r++) {
                int row = tm * 128 + wr * 64 + m * 16 + (lane >> 4) * 4 + r;
                int col = tn * 128 + wc * 64 + n * 16 + (lane & 15);
                out[(size_t)row * DIM + col] = acc[m][n][r] + bias[col];
            }
        }
    }
}

// ---------------- 4. MFMA windowed attention: 1 wave per (head, f, h) row ----------------
// 16 queries (one w-row). Keys: 3 f-chunks x 6 h-rows x 16 w = 288, contiguous per chunk.
// Q pre-scaled by QSCALE at GEMM; softmax = exp2 with no max-sub; normalize at epilogue.
__global__ __launch_bounds__(256) void attn_mfma(
        const _Float16* __restrict__ Q,    // [16][2048][64] (scaled)
        const _Float16* __restrict__ K,    // [16][2048][64]
        const _Float16* __restrict__ Vt,   // [16][64][2048]
        _Float16* __restrict__ AO) {       // [2048][1024]
    __shared__ char P_lds[4][16 * 640];    // per-wave P[16 q][288 key] f16, XOR-swizzled

    int wid  = threadIdx.x >> 6;
    int lane = threadIdx.x & 63;
    int g    = lane >> 4;      // 0..3
    int ql   = lane & 15;

    int bid  = blockIdx.x * 4 + wid;
    int rid  = bid & 127;      // (f,h)
    int head = bid >> 7;
    int f    = rid >> 4;
    int hq   = rid & 15;
    int s0   = rid << 4;

    const _Float16* Qh = Q  + (size_t)head * (SEQ * HD);
    const _Float16* Kh = K  + (size_t)head * (SEQ * HD);
    const _Float16* Vh = Vt + (size_t)head * (HD * SEQ);

    int f_start = min(max(f - 1, 0), 5);
    int h_start = min(max(hq - 2, 0), 10);

    // per-lane w-mask: key w' = g*4+r, query w = ql
    bool wm[4];
    #pragma unroll
    for (int r = 0; r < 4; r++) {
        int wp = g * 4 + r;
        wm[r] = (wp - ql <= 2) && (ql - wp <= 2);
    }

    // Q B-frags (2 k-steps over d=64)
    half8 qf[2];
    #pragma unroll
    for (int ks = 0; ks < 2; ks++)
        qf[ks] = *reinterpret_cast<const half8*>(Qh + (size_t)(s0 + ql) * HD + ks * 32 + g * 8);

    float lsum = 0.f;
    int swz = (ql & 7) << 4;

    #pragma unroll
    for (int fi = 0; fi < 3; fi++) {
        int fp = f_start + fi;
        bool fok = (fp - f <= 1) && (f - fp <= 1);
        int sbase = fp * 256 + h_start * 16;
        const _Float16* Kc = Kh + (size_t)sbase * HD;

        floatx4 sacc[6];
        #pragma unroll
        for (int j = 0; j < 6; j++) sacc[j] = (floatx4){0.f, 0.f, 0.f, 0.f};

        #pragma unroll
        for (int j = 0; j < 6; j++) {
            #pragma unroll
            for (int ks = 0; ks < 2; ks++) {
                half8 kf = *reinterpret_cast<const half8*>(Kc + (size_t)(j * 16 + ql) * HD + ks * 32 + g * 8);
                sacc[j] = __builtin_amdgcn_mfma_f32_16x16x32_f16(kf, qf[ks], sacc[j], 0, 0, 0);
            }
        }

        #pragma unroll
        for (int j = 0; j < 6; j++) {
            int hp = h_start + j;
            bool ok = fok && (hp - hq <= 2) && (hq - hp <= 2);
            half4 pv;
            #pragma unroll
            for (int r = 0; r < 4; r++) {
                float sv = (ok && wm[r]) ? sacc[j][r] : -10000.f;
                float p  = __builtin_amdgcn_exp2f(sv);
                lsum += p;
                pv[r] = (_Float16)p;
            }
            int byte = (ql * 640 + (fi * 96 + j * 16 + g * 4) * 2) ^ swz;
            *reinterpret_cast<half4*>(&P_lds[wid][byte]) = pv;
        }
    }

    // row sums (q = ql lives in 4 lane-groups)
    lsum += __shfl_xor(lsum, 16);
    lsum += __shfl_xor(lsum, 32);
    float inv = __builtin_amdgcn_rcpf(lsum);

    __syncthreads();

    floatx4 oacc[4];
    #pragma unroll
    for (int dt = 0; dt < 4; dt++) oacc[dt] = (floatx4){0.f, 0.f, 0.f, 0.f};

    #pragma unroll
    for (int fi = 0; fi < 3; fi++) {
        int sbase = (f_start + fi) * 256 + h_start * 16;
        #pragma unroll
        for (int kw = 0; kw < 3; kw++) {
            int kcol = fi * 96 + kw * 32;
            int byte = (ql * 640 + (kcol + g * 8) * 2) ^ swz;
            half8 pa = *reinterpret_cast<half8*>(&P_lds[wid][byte]);
            #pragma unroll
            for (int dt = 0; dt < 4; dt++) {
                half8 vf = *reinterpret_cast<const half8*>(
                    Vh + (size_t)(dt * 16 + ql) * SEQ + sbase + kw * 32 + g * 8);
                oacc[dt] = __builtin_amdgcn_mfma_f32_16x16x32_f16(pa, vf, oacc[dt], 0, 0, 0);
            }
        }
    }

    // epilogue: C row = q = g*4+rr, col = d = dt*16+ql; scale by 1/sum
    #pragma unroll
    for (int rr = 0; rr < 4; rr++) {
        float invr = __shfl(inv, g * 4 + rr);
        #pragma unroll
        for (int dt = 0; dt < 4; dt++) {
            AO[(size_t)(s0 + g * 4 + rr) * DIM + head * HD + dt * 16 + ql] =
                (_Float16)(oacc[dt][rr] * invr);
        }
    }
}

// ---------------- launch ----------------
extern "C" void kernel_launch(void* const* d_in, const int* in_sizes, int n_in,
                              void* d_out, int out_size, void* d_ws, size_t ws_size,
                              hipStream_t stream) {
    const float* H  = (const float*)d_in[0];
    const float* Wq = (const float*)d_in[1];
    const float* Wk = (const float*)d_in[2];
    const float* Wv = (const float*)d_in[3];
    const float* Wo = (const float*)d_in[4];
    const float* bo = (const float*)d_in[5];

    char* ws = (char*)d_ws;
    // layout: Hf16 [0,4M) | Wt x4 [4M,12M) | Q [12M,16M) | K [16M,20M) | Vt [20M,24M) | AO [24M,28M)
    _Float16* Hf = (_Float16*)(ws);
    _Float16* Wt = (_Float16*)(ws + (4u  << 20));
    _Float16* Qp = (_Float16*)(ws + (12u << 20));
    _Float16* Kp = (_Float16*)(ws + (16u << 20));
    _Float16* Vt = (_Float16*)(ws + (20u << 20));
    _Float16* AO = (_Float16*)(ws + (24u << 20));

    // 1+2. H -> f16 and weights -> transposed f16 (merged)
    prep<<<dim3(32, 32, 5), dim3(32, 8), 0, stream>>>(H, Hf, Wq, Wk, Wv, Wo, Wt);

    // 3. fused Q, K, V^T projections (z=0,1: QK per-head; z=2: V^T remapped)
    gemm_qkv<<<dim3(16, 8, 3), 256, 0, stream>>>(Hf, Wt, Qp, Kp, Vt);

    // 4. windowed MFMA attention: 2048 one-wave rows, 4 per block
    attn_mfma<<<dim3(NHEAD * 128 / 4), 256, 0, stream>>>(Qp, Kp, Vt, AO);

    // 5. output projection + bias
    gemm_o<<<dim3(16, 8), 256, 0, stream>>>(AO, Wt + (size_t)3 * DIM * DIM, bo, (float*)d_out);
}

// Round 7
// 74.384 us; speedup vs baseline: 1.3157x; 1.0870x over previous
//
#include <hip/hip_runtime.h>
#include <hip/hip_bf16.h>
#include <hip/hip_fp16.h>

// ---------------- constants (problem is fixed-shape) ----------------
#define SEQ   2048
#define DIM   1024
#define NHEAD 16
#define HD    64
// grid (8,16,16), window (3,5,5) -> half windows 1,2,2
#define QSCALE 0.18033688011112042f   // (1/sqrt(64)) * log2(e), folded into Q

typedef _Float16 half8 __attribute__((ext_vector_type(8)));
typedef _Float16 half4 __attribute__((ext_vector_type(4)));
typedef float    floatx4 __attribute__((ext_vector_type(4)));

// async global->LDS, 16B per lane; LDS dest is wave-uniform base + lane*16
__device__ __forceinline__ void gload16(const void* g, void* l) {
    __builtin_amdgcn_global_load_lds(
        (const __attribute__((address_space(1))) unsigned int*)g,
        (__attribute__((address_space(3))) unsigned int*)l, 16, 0, 0);
}

#define VMCNT(n) asm volatile("s_waitcnt vmcnt(" #n ")" ::: "memory")
#define BAR()    __builtin_amdgcn_s_barrier()

// ---------------- 1+2 merged prep: weight transpose-cvt (z 0..3) + H cvt (z 4) ----
__global__ __launch_bounds__(256) void prep(
        const float* __restrict__ H, _Float16* __restrict__ Hf,
        const float* __restrict__ W0, const float* __restrict__ W1,
        const float* __restrict__ W2, const float* __restrict__ W3,
        _Float16* __restrict__ T) {
    __shared__ float tile[32][33];
    int z = blockIdx.z;
    int tx = threadIdx.x, ty = threadIdx.y;
    if (z < 4) {
        const float* W = (z == 0) ? W0 : (z == 1) ? W1 : (z == 2) ? W2 : W3;
        _Float16* Tz = T + (size_t)z * (DIM * DIM);
        int bx = blockIdx.x * 32;   // n-dim base
        int by = blockIdx.y * 32;   // k-dim base
        #pragma unroll
        for (int i = 0; i < 32; i += 8)
            tile[ty + i][tx] = W[(size_t)(by + ty + i) * DIM + bx + tx];
        __syncthreads();
        #pragma unroll
        for (int i = 0; i < 32; i += 8)
            Tz[(size_t)(bx + ty + i) * DIM + by + tx] = (_Float16)tile[tx][ty + i];
    } else {
        // convert H (2M floats): 1024 WGs x 256 threads x 8 elems
        int wg = blockIdx.y * 32 + blockIdx.x;
        int lt = ty * 32 + tx;
        int base = (wg * 256 + lt) * 8;
        float4 v0 = *reinterpret_cast<const float4*>(H + base);
        float4 v1 = *reinterpret_cast<const float4*>(H + base + 4);
        half8 o = { (_Float16)v0.x, (_Float16)v0.y, (_Float16)v0.z, (_Float16)v0.w,
                    (_Float16)v1.x, (_Float16)v1.y, (_Float16)v1.z, (_Float16)v1.w };
        *reinterpret_cast<half8*>(Hf + base) = o;
    }
}

// ---------------- GEMM core: 128x128 tile, BK=32, 2-deep counted-vmcnt pipeline ----
// A_tile, B_tile row-major, K-stride DIM, K=1024. 256 threads = 4 waves (2x2);
// wave = 64x64 = 4x4 frags of mfma_f32_16x16x32_f16.
// LDS per buffer: A [128][32] f16 (8KB) + B [128][32] (8KB); 2 buffers = 32KB.
// Pipeline (T3+T4): two K-steps in flight; per-step wait is vmcnt(4) (the older
// buffer's 4 loads), NEVER 0 in the main loop. Per-wave vmcnt + barrier rendezvous
// => whole buffer present. Barrier after compute protects overwrite.
__device__ __forceinline__ void gemm_core(const _Float16* __restrict__ Ap,
                                          const _Float16* __restrict__ Bp,
                                          char* lds, floatx4 (&acc)[4][4]) {
    const int tid  = threadIdx.x;
    const int lane = tid & 63;
    const int wid  = tid >> 6;
    const int wr = wid >> 1, wc = wid & 1;
    const int r16 = lane & 15;
    const int kk  = (lane >> 4) * 8;

    // staging map: LDS byte (i*4096 + tid*16) <-> elem row = i*64 + (tid>>2), col = (tid&3)*8
    const int srow = tid >> 2, scol = (tid & 3) * 8;
    const _Float16* As0 = Ap + (size_t)srow * DIM + scol;
    const _Float16* Bs0 = Bp + (size_t)srow * DIM + scol;

    auto stage = [&](int buf, int t) {     // t = K-step index (BK=32)
        char* Ad = lds + buf * 16384;
        char* Bd = Ad + 8192;
        int k0 = t * 32;
        #pragma unroll
        for (int i = 0; i < 2; i++) {
            gload16(As0 + (size_t)i * 64 * DIM + k0, Ad + i * 4096 + wid * 1024);
            gload16(Bs0 + (size_t)i * 64 * DIM + k0, Bd + i * 4096 + wid * 1024);
        }
    };

    auto compute = [&](int buf) {
        char* Ad = lds + buf * 16384;
        char* Bd = Ad + 8192;
        half8 a[4], b[4];
        #pragma unroll
        for (int m = 0; m < 4; m++)
            a[m] = *reinterpret_cast<half8*>(Ad + (wr * 64 + m * 16 + r16) * 64 + kk * 2);
        #pragma unroll
        for (int n = 0; n < 4; n++)
            b[n] = *reinterpret_cast<half8*>(Bd + (wc * 64 + n * 16 + r16) * 64 + kk * 2);
        #pragma unroll
        for (int m = 0; m < 4; m++)
            #pragma unroll
            for (int n = 0; n < 4; n++)
                acc[m][n] = __builtin_amdgcn_mfma_f32_16x16x32_f16(a[m], b[n], acc[m][n], 0, 0, 0);
    };

    stage(0, 0);
    stage(1, 1);                               // 8 loads/wave outstanding
    #pragma unroll 1
    for (int t = 0; t < 30; t += 2) {
        VMCNT(4); BAR();                       // buf0 (step t) ready everywhere
        compute(0);
        BAR();                                 // all waves done reading buf0
        stage(0, t + 2);                       // 8 outstanding
        VMCNT(4); BAR();                       // buf1 (step t+1) ready
        compute(1);
        BAR();
        stage(1, t + 3);                       // 8 outstanding
    }
    // steps 30, 31 (peeled; no more staging)
    VMCNT(4); BAR();
    compute(0);
    BAR();
    VMCNT(0); BAR();
    compute(1);
}

// ---------------- 3. fused QKV projections ----------------
// z=0: Q = H*Wq^T (scaled, per-head layout)  z=1: K (per-head layout)
// z=2: V^T = Wv^T * H^T  (row-major [1024][2048]), tiles remapped from 16x8 grid
__global__ __launch_bounds__(256) void gemm_qkv(
        const _Float16* __restrict__ Hf, const _Float16* __restrict__ Wt,
        _Float16* __restrict__ Qp, _Float16* __restrict__ Kp, _Float16* __restrict__ Vt) {
    __shared__ char lds[32768];
    floatx4 acc[4][4] = {};

    int z = blockIdx.z;
    int tm, tn;
    const _Float16 *Ap, *Bp;
    if (z < 2) {
        tm = blockIdx.x; tn = blockIdx.y;                      // 16 x 8
        Ap = Hf + (size_t)tm * 128 * DIM;
        Bp = Wt + (size_t)z * DIM * DIM + (size_t)tn * 128 * DIM;
    } else {
        tm = blockIdx.x & 7; tn = blockIdx.y * 2 + (blockIdx.x >> 3);  // 8 x 16
        Ap = Wt + (size_t)2 * DIM * DIM + (size_t)tm * 128 * DIM;
        Bp = Hf + (size_t)tn * 128 * DIM;
    }
    gemm_core(Ap, Bp, lds, acc);

    int lane = threadIdx.x & 63, wid = threadIdx.x >> 6;
    int wr = wid >> 1, wc = wid & 1;
    float qs = (z == 0) ? QSCALE : 1.0f;
    _Float16* Oz = (z == 0) ? Qp : Kp;

    #pragma unroll
    for (int m = 0; m < 4; m++) {
        #pragma unroll
        for (int n = 0; n < 4; n++) {
            #pragma unroll
            for (int r = 0; r < 4; r++) {
                int row = tm * 128 + wr * 64 + m * 16 + (lane >> 4) * 4 + r;
                int col = tn * 128 + wc * 64 + n * 16 + (lane & 15);
                float v = acc[m][n][r];
                if (z < 2) {
                    int head = col >> 6;
                    Oz[(size_t)head * (SEQ * HD) + (size_t)row * HD + (col & 63)] = (_Float16)(v * qs);
                } else {
                    Vt[(size_t)row * SEQ + col] = (_Float16)v;
                }
            }
        }
    }
}

// ---------------- 5. output projection + bias ----------------
__global__ __launch_bounds__(256) void gemm_o(
        const _Float16* __restrict__ AO, const _Float16* __restrict__ WoT,
        const float* __restrict__ bias, float* __restrict__ out) {
    __shared__ char lds[32768];
    floatx4 acc[4][4] = {};

    int tm = blockIdx.x, tn = blockIdx.y;                      // 16 x 8
    gemm_core(AO + (size_t)tm * 128 * DIM, WoT + (size_t)tn * 128 * DIM, lds, acc);

    int lane = threadIdx.x & 63, wid = threadIdx.x >> 6;
    int wr = wid >> 1, wc = wid & 1;
    #pragma unroll
    for (int m = 0; m < 4; m++) {
        #pragma unroll
        for (int n = 0; n < 4; n++) {
            #pragma unroll
            for (int r = 0; r < 4; r++) {
                int row = tm * 128 + wr * 64 + m * 16 + (lane >> 4) * 4 + r;
                int col = tn * 128 + wc * 64 + n * 16 + (lane & 15);
                out[(size_t)row * DIM + col] = acc[m][n][r] + bias[col];
            }
        }
    }
}

// ---------------- 4. MFMA windowed attention: 1 wave per (head, f, h) row ----------------
// 16 queries (one w-row). Keys: 3 f-chunks x 6 h-rows x 16 w = 288, contiguous per chunk.
// Q pre-scaled by QSCALE at GEMM; softmax = exp2 with no max-sub; normalize at epilogue.
__global__ __launch_bounds__(256) void attn_mfma(
        const _Float16* __restrict__ Q,    // [16][2048][64] (scaled)
        const _Float16* __restrict__ K,    // [16][2048][64]
        const _Float16* __restrict__ Vt,   // [16][64][2048]
        _Float16* __restrict__ AO) {       // [2048][1024]
    __shared__ char P_lds[4][16 * 640];    // per-wave P[16 q][288 key] f16, XOR-swizzled

    int wid  = threadIdx.x >> 6;
    int lane = threadIdx.x & 63;
    int g    = lane >> 4;      // 0..3
    int ql   = lane & 15;

    int bid  = blockIdx.x * 4 + wid;
    int rid  = bid & 127;      // (f,h)
    int head = bid >> 7;
    int f    = rid >> 4;
    int hq   = rid & 15;
    int s0   = rid << 4;

    const _Float16* Qh = Q  + (size_t)head * (SEQ * HD);
    const _Float16* Kh = K  + (size_t)head * (SEQ * HD);
    const _Float16* Vh = Vt + (size_t)head * (HD * SEQ);

    int f_start = min(max(f - 1, 0), 5);
    int h_start = min(max(hq - 2, 0), 10);

    // per-lane w-mask: key w' = g*4+r, query w = ql
    bool wm[4];
    #pragma unroll
    for (int r = 0; r < 4; r++) {
        int wp = g * 4 + r;
        wm[r] = (wp - ql <= 2) && (ql - wp <= 2);
    }

    // Q B-frags (2 k-steps over d=64)
    half8 qf[2];
    #pragma unroll
    for (int ks = 0; ks < 2; ks++)
        qf[ks] = *reinterpret_cast<const half8*>(Qh + (size_t)(s0 + ql) * HD + ks * 32 + g * 8);

    float lsum = 0.f;
    int swz = (ql & 7) << 4;

    #pragma unroll
    for (int fi = 0; fi < 3; fi++) {
        int fp = f_start + fi;
        bool fok = (fp - f <= 1) && (f - fp <= 1);
        int sbase = fp * 256 + h_start * 16;
        const _Float16* Kc = Kh + (size_t)sbase * HD;

        floatx4 sacc[6];
        #pragma unroll
        for (int j = 0; j < 6; j++) sacc[j] = (floatx4){0.f, 0.f, 0.f, 0.f};

        #pragma unroll
        for (int j = 0; j < 6; j++) {
            #pragma unroll
            for (int ks = 0; ks < 2; ks++) {
                half8 kf = *reinterpret_cast<const half8*>(Kc + (size_t)(j * 16 + ql) * HD + ks * 32 + g * 8);
                sacc[j] = __builtin_amdgcn_mfma_f32_16x16x32_f16(kf, qf[ks], sacc[j], 0, 0, 0);
            }
        }

        #pragma unroll
        for (int j = 0; j < 6; j++) {
            int hp = h_start + j;
            bool ok = fok && (hp - hq <= 2) && (hq - hp <= 2);
            half4 pv;
            #pragma unroll
            for (int r = 0; r < 4; r++) {
                float sv = (ok && wm[r]) ? sacc[j][r] : -10000.f;
                float p  = __builtin_amdgcn_exp2f(sv);
                lsum += p;
                pv[r] = (_Float16)p;
            }
            int byte = (ql * 640 + (fi * 96 + j * 16 + g * 4) * 2) ^ swz;
            *reinterpret_cast<half4*>(&P_lds[wid][byte]) = pv;
        }
    }

    // row sums (q = ql lives in 4 lane-groups)
    lsum += __shfl_xor(lsum, 16);
    lsum += __shfl_xor(lsum, 32);
    float inv = __builtin_amdgcn_rcpf(lsum);

    __syncthreads();

    floatx4 oacc[4];
    #pragma unroll
    for (int dt = 0; dt < 4; dt++) oacc[dt] = (floatx4){0.f, 0.f, 0.f, 0.f};

    #pragma unroll
    for (int fi = 0; fi < 3; fi++) {
        int sbase = (f_start + fi) * 256 + h_start * 16;
        #pragma unroll
        for (int kw = 0; kw < 3; kw++) {
            int kcol = fi * 96 + kw * 32;
            int byte = (ql * 640 + (kcol + g * 8) * 2) ^ swz;
            half8 pa = *reinterpret_cast<half8*>(&P_lds[wid][byte]);
            #pragma unroll
            for (int dt = 0; dt < 4; dt++) {
                half8 vf = *reinterpret_cast<const half8*>(
                    Vh + (size_t)(dt * 16 + ql) * SEQ + sbase + kw * 32 + g * 8);
                oacc[dt] = __builtin_amdgcn_mfma_f32_16x16x32_f16(pa, vf, oacc[dt], 0, 0, 0);
            }
        }
    }

    // epilogue: C row = q = g*4+rr, col = d = dt*16+ql; scale by 1/sum
    #pragma unroll
    for (int rr = 0; rr < 4; rr++) {
        float invr = __shfl(inv, g * 4 + rr);
        #pragma unroll
        for (int dt = 0; dt < 4; dt++) {
            AO[(size_t)(s0 + g * 4 + rr) * DIM + head * HD + dt * 16 + ql] =
                (_Float16)(oacc[dt][rr] * invr);
        }
    }
}

// ---------------- launch ----------------
extern "C" void kernel_launch(void* const* d_in, const int* in_sizes, int n_in,
                              void* d_out, int out_size, void* d_ws, size_t ws_size,
                              hipStream_t stream) {
    const float* H  = (const float*)d_in[0];
    const float* Wq = (const float*)d_in[1];
    const float* Wk = (const float*)d_in[2];
    const float* Wv = (const float*)d_in[3];
    const float* Wo = (const float*)d_in[4];
    const float* bo = (const float*)d_in[5];

    char* ws = (char*)d_ws;
    // layout: Hf16 [0,4M) | Wt x4 [4M,12M) | Q [12M,16M) | K [16M,20M) | Vt [20M,24M) | AO [24M,28M)
    _Float16* Hf = (_Float16*)(ws);
    _Float16* Wt = (_Float16*)(ws + (4u  << 20));
    _Float16* Qp = (_Float16*)(ws + (12u << 20));
    _Float16* Kp = (_Float16*)(ws + (16u << 20));
    _Float16* Vt = (_Float16*)(ws + (20u << 20));
    _Float16* AO = (_Float16*)(ws + (24u << 20));

    // 1+2. H -> f16 and weights -> transposed f16 (merged)
    prep<<<dim3(32, 32, 5), dim3(32, 8), 0, stream>>>(H, Hf, Wq, Wk, Wv, Wo, Wt);

    // 3. fused Q, K, V^T projections (z=0,1: QK per-head; z=2: V^T remapped)
    gemm_qkv<<<dim3(16, 8, 3), 256, 0, stream>>>(Hf, Wt, Qp, Kp, Vt);

    // 4. windowed MFMA attention: 2048 one-wave rows, 4 per block
    attn_mfma<<<dim3(NHEAD * 128 / 4), 256, 0, stream>>>(Qp, Kp, Vt, AO);

    // 5. output projection + bias
    gemm_o<<<dim3(16, 8), 256, 0, stream>>>(AO, Wt + (size_t)3 * DIM * DIM, bo, (float*)d_out);
}

// Round 8
// 70.207 us; speedup vs baseline: 1.3940x; 1.0595x over previous
//
#include <hip/hip_runtime.h>
#include <hip/hip_bf16.h>
#include <hip/hip_fp16.h>

// ---------------- constants (problem is fixed-shape) ----------------
#define SEQ   2048
#define DIM   1024
#define NHEAD 16
#define HD    64
// grid (8,16,16), window (3,5,5) -> half windows 1,2,2
#define QSCALE 0.18033688011112042f   // (1/sqrt(64)) * log2(e), folded into Q

typedef _Float16 half8 __attribute__((ext_vector_type(8)));
typedef _Float16 half4 __attribute__((ext_vector_type(4)));
typedef float    floatx4 __attribute__((ext_vector_type(4)));

// async global->LDS, 16B per lane; LDS dest is wave-uniform base + lane*16
__device__ __forceinline__ void gload16(const void* g, void* l) {
    __builtin_amdgcn_global_load_lds(
        (const __attribute__((address_space(1))) unsigned int*)g,
        (__attribute__((address_space(3))) unsigned int*)l, 16, 0, 0);
}

#define VMCNT(n) asm volatile("s_waitcnt vmcnt(" #n ")" ::: "memory")
#define BAR()    __builtin_amdgcn_s_barrier()

// ---------------- 1+2 merged prep (vectorized) ----------------
// z<4: 64x64 transpose-cvt tiles through padded LDS (float4 loads, half8 stores)
// z=4: H f32->f16, float4 x2 -> half8, 32 elems/thread
__global__ __launch_bounds__(256) void prep(
        const float* __restrict__ H, _Float16* __restrict__ Hf,
        const float* __restrict__ W0, const float* __restrict__ W1,
        const float* __restrict__ W2, const float* __restrict__ W3,
        _Float16* __restrict__ T) {
    __shared__ float tile[64][65];    // +1 pad: both phases <=2-way bank aliasing
    int z = blockIdx.z;
    int t = threadIdx.x;
    if (z < 4) {
        const float* W = (z == 0) ? W0 : (z == 1) ? W1 : (z == 2) ? W2 : W3;
        _Float16* Tz = T + (size_t)z * (DIM * DIM);
        int bx = blockIdx.x * 64;     // n base
        int by = blockIdx.y * 64;     // k base
        #pragma unroll
        for (int i = 0; i < 4; i++) {
            int id = t + i * 256;
            int r = id >> 4;                  // k_local 0..63
            int c = (id & 15) * 4;            // n_local 0..60
            float4 v = *reinterpret_cast<const float4*>(W + (size_t)(by + r) * DIM + bx + c);
            tile[r][c] = v.x; tile[r][c + 1] = v.y; tile[r][c + 2] = v.z; tile[r][c + 3] = v.w;
        }
        __syncthreads();
        #pragma unroll
        for (int i = 0; i < 2; i++) {
            int id = t + i * 256;
            int nr = id >> 3;                 // n_local 0..63
            int c8 = id & 7;                  // k chunk
            half8 o;
            #pragma unroll
            for (int j = 0; j < 8; j++) o[j] = (_Float16)tile[c8 * 8 + j][nr];
            *reinterpret_cast<half8*>(Tz + (size_t)(bx + nr) * DIM + by + c8 * 8) = o;
        }
    } else {
        int wg = blockIdx.y * 16 + blockIdx.x;   // 0..255
        #pragma unroll
        for (int i = 0; i < 4; i++) {
            int base = ((wg * 4 + i) * 256 + t) * 8;
            float4 v0 = *reinterpret_cast<const float4*>(H + base);
            float4 v1 = *reinterpret_cast<const float4*>(H + base + 4);
            half8 o = { (_Float16)v0.x, (_Float16)v0.y, (_Float16)v0.z, (_Float16)v0.w,
                        (_Float16)v1.x, (_Float16)v1.y, (_Float16)v1.z, (_Float16)v1.w };
            *reinterpret_cast<half8*>(Hf + base) = o;
        }
    }
}

// ---------------- GEMM core: 128x128 tile, BK=32, 2-deep counted-vmcnt pipeline ----
// (unchanged from round 7 — proven structure)
__device__ __forceinline__ void gemm_core(const _Float16* __restrict__ Ap,
                                          const _Float16* __restrict__ Bp,
                                          char* lds, floatx4 (&acc)[4][4]) {
    const int tid  = threadIdx.x;
    const int lane = tid & 63;
    const int wid  = tid >> 6;
    const int wr = wid >> 1, wc = wid & 1;
    const int r16 = lane & 15;
    const int kk  = (lane >> 4) * 8;

    const int srow = tid >> 2, scol = (tid & 3) * 8;
    const _Float16* As0 = Ap + (size_t)srow * DIM + scol;
    const _Float16* Bs0 = Bp + (size_t)srow * DIM + scol;

    auto stage = [&](int buf, int t) {     // t = K-step index (BK=32)
        char* Ad = lds + buf * 16384;
        char* Bd = Ad + 8192;
        int k0 = t * 32;
        #pragma unroll
        for (int i = 0; i < 2; i++) {
            gload16(As0 + (size_t)i * 64 * DIM + k0, Ad + i * 4096 + wid * 1024);
            gload16(Bs0 + (size_t)i * 64 * DIM + k0, Bd + i * 4096 + wid * 1024);
        }
    };

    auto compute = [&](int buf) {
        char* Ad = lds + buf * 16384;
        char* Bd = Ad + 8192;
        half8 a[4], b[4];
        #pragma unroll
        for (int m = 0; m < 4; m++)
            a[m] = *reinterpret_cast<half8*>(Ad + (wr * 64 + m * 16 + r16) * 64 + kk * 2);
        #pragma unroll
        for (int n = 0; n < 4; n++)
            b[n] = *reinterpret_cast<half8*>(Bd + (wc * 64 + n * 16 + r16) * 64 + kk * 2);
        #pragma unroll
        for (int m = 0; m < 4; m++)
            #pragma unroll
            for (int n = 0; n < 4; n++)
                acc[m][n] = __builtin_amdgcn_mfma_f32_16x16x32_f16(a[m], b[n], acc[m][n], 0, 0, 0);
    };

    stage(0, 0);
    stage(1, 1);                               // 8 loads/wave outstanding
    #pragma unroll 1
    for (int t = 0; t < 30; t += 2) {
        VMCNT(4); BAR();                       // buf0 (step t) ready everywhere
        compute(0);
        BAR();                                 // all waves done reading buf0
        stage(0, t + 2);                       // 8 outstanding
        VMCNT(4); BAR();                       // buf1 (step t+1) ready
        compute(1);
        BAR();
        stage(1, t + 3);                       // 8 outstanding
    }
    VMCNT(4); BAR();
    compute(0);
    BAR();
    VMCNT(0); BAR();
    compute(1);
}

// ---------------- 3. fused QKV projections (XCD-swizzled tile ids) ----------------
// z=0: Q = H*Wq^T (scaled, per-head layout)  z=1: K (per-head layout)
// z=2: V^T = Wv^T * H^T  (row-major [1024][2048]), tiles remapped from 16x8 grid
__global__ __launch_bounds__(256) void gemm_qkv(
        const _Float16* __restrict__ Hf, const _Float16* __restrict__ Wt,
        _Float16* __restrict__ Qp, _Float16* __restrict__ Kp, _Float16* __restrict__ Vt) {
    __shared__ char lds[32768];
    floatx4 acc[4][4] = {};

    // XCD-aware chunked remap of the 384 workgroups (384 % 8 == 0 -> bijective):
    // each XCD gets 48 consecutive tiles (same B-panel reused within an XCD's L2)
    int lin = blockIdx.x + 16 * blockIdx.y + 128 * blockIdx.z;   // 0..383
    int swz = (lin & 7) * 48 + (lin >> 3);
    int z  = swz >> 7;            // 0..2
    int rem = swz & 127;
    int bx = rem & 15, by = rem >> 4;    // bx 0..15, by 0..7

    int tm, tn;
    const _Float16 *Ap, *Bp;
    if (z < 2) {
        tm = bx; tn = by;                                       // 16 x 8
        Ap = Hf + (size_t)tm * 128 * DIM;
        Bp = Wt + (size_t)z * DIM * DIM + (size_t)tn * 128 * DIM;
    } else {
        tm = bx & 7; tn = by * 2 + (bx >> 3);                   // 8 x 16
        Ap = Wt + (size_t)2 * DIM * DIM + (size_t)tm * 128 * DIM;
        Bp = Hf + (size_t)tn * 128 * DIM;
    }
    gemm_core(Ap, Bp, lds, acc);

    int lane = threadIdx.x & 63, wid = threadIdx.x >> 6;
    int wr = wid >> 1, wc = wid & 1;
    float qs = (z == 0) ? QSCALE : 1.0f;
    _Float16* Oz = (z == 0) ? Qp : Kp;

    #pragma unroll
    for (int m = 0; m < 4; m++) {
        #pragma unroll
        for (int n = 0; n < 4; n++) {
            #pragma unroll
            for (int r = 0; r < 4; r++) {
                int row = tm * 128 + wr * 64 + m * 16 + (lane >> 4) * 4 + r;
                int col = tn * 128 + wc * 64 + n * 16 + (lane & 15);
                float v = acc[m][n][r];
                if (z < 2) {
                    int head = col >> 6;
                    Oz[(size_t)head * (SEQ * HD) + (size_t)row * HD + (col & 63)] = (_Float16)(v * qs);
                } else {
                    Vt[(size_t)row * SEQ + col] = (_Float16)v;
                }
            }
        }
    }
}

// ---------------- 5. output projection + bias (XCD-swizzled) ----------------
__global__ __launch_bounds__(256) void gemm_o(
        const _Float16* __restrict__ AO, const _Float16* __restrict__ WoT,
        const float* __restrict__ bias, float* __restrict__ out) {
    __shared__ char lds[32768];
    floatx4 acc[4][4] = {};

    int lin = blockIdx.x + 16 * blockIdx.y;      // 0..127
    int swz = (lin & 7) * 16 + (lin >> 3);       // 128 % 8 == 0 -> bijective
    int tm = swz & 15, tn = swz >> 4;            // 16 x 8

    gemm_core(AO + (size_t)tm * 128 * DIM, WoT + (size_t)tn * 128 * DIM, lds, acc);

    int lane = threadIdx.x & 63, wid = threadIdx.x >> 6;
    int wr = wid >> 1, wc = wid & 1;
    #pragma unroll
    for (int m = 0; m < 4; m++) {
        #pragma unroll
        for (int n = 0; n < 4; n++) {
            #pragma unroll
            for (int r = 0; r < 4; r++) {
                int row = tm * 128 + wr * 64 + m * 16 + (lane >> 4) * 4 + r;
                int col = tn * 128 + wc * 64 + n * 16 + (lane & 15);
                out[(size_t)row * DIM + col] = acc[m][n][r] + bias[col];
            }
        }
    }
}

// ---------------- 4. MFMA windowed attention (XCD-swizzled blocks) ----------------
// 1 wave per (head, f, h) row; 16 queries. Keys: 3 f-chunks x 6 h-rows x 16 w = 288.
// Swizzle: each XCD gets 64 consecutive blocks = 2 heads -> K/V (1MB) resident in
// its private 4MB L2 instead of re-fetching through L3.
__global__ __launch_bounds__(256) void attn_mfma(
        const _Float16* __restrict__ Q,    // [16][2048][64] (scaled)
        const _Float16* __restrict__ K,    // [16][2048][64]
        const _Float16* __restrict__ Vt,   // [16][64][2048]
        _Float16* __restrict__ AO) {       // [2048][1024]
    __shared__ char P_lds[4][16 * 640];    // per-wave P[16 q][288 key] f16, XOR-swizzled

    int wid  = threadIdx.x >> 6;
    int lane = threadIdx.x & 63;
    int g    = lane >> 4;      // 0..3
    int ql   = lane & 15;

    int blk  = blockIdx.x;                 // 0..511
    int sblk = (blk & 7) * 64 + (blk >> 3);  // XCD-chunked, bijective (512 % 8 == 0)
    int bid  = sblk * 4 + wid;
    int rid  = bid & 127;      // (f,h)
    int head = bid >> 7;
    int f    = rid >> 4;
    int hq   = rid & 15;
    int s0   = rid << 4;

    const _Float16* Qh = Q  + (size_t)head * (SEQ * HD);
    const _Float16* Kh = K  + (size_t)head * (SEQ * HD);
    const _Float16* Vh = Vt + (size_t)head * (HD * SEQ);

    int f_start = min(max(f - 1, 0), 5);
    int h_start = min(max(hq - 2, 0), 10);

    // per-lane w-mask: key w' = g*4+r, query w = ql
    bool wm[4];
    #pragma unroll
    for (int r = 0; r < 4; r++) {
        int wp = g * 4 + r;
        wm[r] = (wp - ql <= 2) && (ql - wp <= 2);
    }

    // Q B-frags (2 k-steps over d=64)
    half8 qf[2];
    #pragma unroll
    for (int ks = 0; ks < 2; ks++)
        qf[ks] = *reinterpret_cast<const half8*>(Qh + (size_t)(s0 + ql) * HD + ks * 32 + g * 8);

    float lsum = 0.f;
    int swz = (ql & 7) << 4;

    #pragma unroll
    for (int fi = 0; fi < 3; fi++) {
        int fp = f_start + fi;
        bool fok = (fp - f <= 1) && (f - fp <= 1);
        int sbase = fp * 256 + h_start * 16;
        const _Float16* Kc = Kh + (size_t)sbase * HD;

        floatx4 sacc[6];
        #pragma unroll
        for (int j = 0; j < 6; j++) sacc[j] = (floatx4){0.f, 0.f, 0.f, 0.f};

        #pragma unroll
        for (int j = 0; j < 6; j++) {
            #pragma unroll
            for (int ks = 0; ks < 2; ks++) {
                half8 kf = *reinterpret_cast<const half8*>(Kc + (size_t)(j * 16 + ql) * HD + ks * 32 + g * 8);
                sacc[j] = __builtin_amdgcn_mfma_f32_16x16x32_f16(kf, qf[ks], sacc[j], 0, 0, 0);
            }
        }

        #pragma unroll
        for (int j = 0; j < 6; j++) {
            int hp = h_start + j;
            bool ok = fok && (hp - hq <= 2) && (hq - hp <= 2);
            half4 pv;
            #pragma unroll
            for (int r = 0; r < 4; r++) {
                float sv = (ok && wm[r]) ? sacc[j][r] : -10000.f;
                float p  = __builtin_amdgcn_exp2f(sv);
                lsum += p;
                pv[r] = (_Float16)p;
            }
            int byte = (ql * 640 + (fi * 96 + j * 16 + g * 4) * 2) ^ swz;
            *reinterpret_cast<half4*>(&P_lds[wid][byte]) = pv;
        }
    }

    // row sums (q = ql lives in 4 lane-groups)
    lsum += __shfl_xor(lsum, 16);
    lsum += __shfl_xor(lsum, 32);
    float inv = __builtin_amdgcn_rcpf(lsum);

    __syncthreads();

    floatx4 oacc[4];
    #pragma unroll
    for (int dt = 0; dt < 4; dt++) oacc[dt] = (floatx4){0.f, 0.f, 0.f, 0.f};

    #pragma unroll
    for (int fi = 0; fi < 3; fi++) {
        int sbase = (f_start + fi) * 256 + h_start * 16;
        #pragma unroll
        for (int kw = 0; kw < 3; kw++) {
            int kcol = fi * 96 + kw * 32;
            int byte = (ql * 640 + (kcol + g * 8) * 2) ^ swz;
            half8 pa = *reinterpret_cast<half8*>(&P_lds[wid][byte]);
            #pragma unroll
            for (int dt = 0; dt < 4; dt++) {
                half8 vf = *reinterpret_cast<const half8*>(
                    Vh + (size_t)(dt * 16 + ql) * SEQ + sbase + kw * 32 + g * 8);
                oacc[dt] = __builtin_amdgcn_mfma_f32_16x16x32_f16(pa, vf, oacc[dt], 0, 0, 0);
            }
        }
    }

    // epilogue: C row = q = g*4+rr, col = d = dt*16+ql; scale by 1/sum
    #pragma unroll
    for (int rr = 0; rr < 4; rr++) {
        float invr = __shfl(inv, g * 4 + rr);
        #pragma unroll
        for (int dt = 0; dt < 4; dt++) {
            AO[(size_t)(s0 + g * 4 + rr) * DIM + head * HD + dt * 16 + ql] =
                (_Float16)(oacc[dt][rr] * invr);
        }
    }
}

// ---------------- launch ----------------
extern "C" void kernel_launch(void* const* d_in, const int* in_sizes, int n_in,
                              void* d_out, int out_size, void* d_ws, size_t ws_size,
                              hipStream_t stream) {
    const float* H  = (const float*)d_in[0];
    const float* Wq = (const float*)d_in[1];
    const float* Wk = (const float*)d_in[2];
    const float* Wv = (const float*)d_in[3];
    const float* Wo = (const float*)d_in[4];
    const float* bo = (const float*)d_in[5];

    char* ws = (char*)d_ws;
    // layout: Hf16 [0,4M) | Wt x4 [4M,12M) | Q [12M,16M) | K [16M,20M) | Vt [20M,24M) | AO [24M,28M)
    _Float16* Hf = (_Float16*)(ws);
    _Float16* Wt = (_Float16*)(ws + (4u  << 20));
    _Float16* Qp = (_Float16*)(ws + (12u << 20));
    _Float16* Kp = (_Float16*)(ws + (16u << 20));
    _Float16* Vt = (_Float16*)(ws + (20u << 20));
    _Float16* AO = (_Float16*)(ws + (24u << 20));

    // 1+2. H -> f16 and weights -> transposed f16 (vectorized)
    prep<<<dim3(16, 16, 5), 256, 0, stream>>>(H, Hf, Wq, Wk, Wv, Wo, Wt);

    // 3. fused Q, K, V^T projections (z=0,1: QK per-head; z=2: V^T remapped)
    gemm_qkv<<<dim3(16, 8, 3), 256, 0, stream>>>(Hf, Wt, Qp, Kp, Vt);

    // 4. windowed MFMA attention: 2048 one-wave rows, 4 per block
    attn_mfma<<<dim3(NHEAD * 128 / 4), 256, 0, stream>>>(Qp, Kp, Vt, AO);

    // 5. output projection + bias
    gemm_o<<<dim3(16, 8), 256, 0, stream>>>(AO, Wt + (size_t)3 * DIM * DIM, bo, (float*)d_out);
}

// Round 9
// 66.989 us; speedup vs baseline: 1.4610x; 1.0480x over previous
//
#include <hip/hip_runtime.h>
#include <hip/hip_bf16.h>
#include <hip/hip_fp16.h>

// ---------------- constants (problem is fixed-shape) ----------------
#define SEQ   2048
#define DIM   1024
#define NHEAD 16
#define HD    64
// grid (8,16,16), window (3,5,5) -> half windows 1,2,2
#define QSCALE 0.18033688011112042f   // (1/sqrt(64)) * log2(e), folded into Q

typedef _Float16 half8 __attribute__((ext_vector_type(8)));
typedef _Float16 half4 __attribute__((ext_vector_type(4)));
typedef float    floatx4 __attribute__((ext_vector_type(4)));

// async global->LDS, 16B per lane; LDS dest is wave-uniform base + lane*16
__device__ __forceinline__ void gload16(const void* g, void* l) {
    __builtin_amdgcn_global_load_lds(
        (const __attribute__((address_space(1))) unsigned int*)g,
        (__attribute__((address_space(3))) unsigned int*)l, 16, 0, 0);
}

#define VMCNT(n) asm volatile("s_waitcnt vmcnt(" #n ")" ::: "memory")
#define BAR()    __builtin_amdgcn_s_barrier()

// ---------------- 1+2 merged prep (vectorized) ----------------
// z<4: 64x64 transpose-cvt tiles through padded LDS (float4 loads, half8 stores)
// z=4: H f32->f16, float4 x2 -> half8, 32 elems/thread
__global__ __launch_bounds__(256) void prep(
        const float* __restrict__ H, _Float16* __restrict__ Hf,
        const float* __restrict__ W0, const float* __restrict__ W1,
        const float* __restrict__ W2, const float* __restrict__ W3,
        _Float16* __restrict__ T) {
    __shared__ float tile[64][65];    // +1 pad: both phases <=2-way bank aliasing
    int z = blockIdx.z;
    int t = threadIdx.x;
    if (z < 4) {
        const float* W = (z == 0) ? W0 : (z == 1) ? W1 : (z == 2) ? W2 : W3;
        _Float16* Tz = T + (size_t)z * (DIM * DIM);
        int bx = blockIdx.x * 64;     // n base
        int by = blockIdx.y * 64;     // k base
        #pragma unroll
        for (int i = 0; i < 4; i++) {
            int id = t + i * 256;
            int r = id >> 4;                  // k_local 0..63
            int c = (id & 15) * 4;            // n_local 0..60
            float4 v = *reinterpret_cast<const float4*>(W + (size_t)(by + r) * DIM + bx + c);
            tile[r][c] = v.x; tile[r][c + 1] = v.y; tile[r][c + 2] = v.z; tile[r][c + 3] = v.w;
        }
        __syncthreads();
        #pragma unroll
        for (int i = 0; i < 2; i++) {
            int id = t + i * 256;
            int nr = id >> 3;                 // n_local 0..63
            int c8 = id & 7;                  // k chunk
            half8 o;
            #pragma unroll
            for (int j = 0; j < 8; j++) o[j] = (_Float16)tile[c8 * 8 + j][nr];
            *reinterpret_cast<half8*>(Tz + (size_t)(bx + nr) * DIM + by + c8 * 8) = o;
        }
    } else {
        int wg = blockIdx.y * 16 + blockIdx.x;   // 0..255
        #pragma unroll
        for (int i = 0; i < 4; i++) {
            int base = ((wg * 4 + i) * 256 + t) * 8;
            float4 v0 = *reinterpret_cast<const float4*>(H + base);
            float4 v1 = *reinterpret_cast<const float4*>(H + base + 4);
            half8 o = { (_Float16)v0.x, (_Float16)v0.y, (_Float16)v0.z, (_Float16)v0.w,
                        (_Float16)v1.x, (_Float16)v1.y, (_Float16)v1.z, (_Float16)v1.w };
            *reinterpret_cast<half8*>(Hf + base) = o;
        }
    }
}

// ---------------- GEMM core: 128x128 tile, BK=64, 2-deep counted-vmcnt pipeline ----
// 256 threads = 4 waves (2x2); wave = 64x64 = 4x4 frags of mfma_f32_16x16x32_f16,
// x2 k-subtiles per BK=64 step -> 32 MFMA per wave per step (barriers halved vs BK=32).
// LDS per buffer: A two [128][32] ks-halves (16KB) + B same (16KB); 2 buffers = 64KB.
// (Grid is ~1.5 blocks/CU, so the 2-blocks/CU LDS cap does not bind.)
// Pipeline (T3+T4): vmcnt(8) = older buffer's 8 loads complete; NEVER 0 in main loop.
__device__ __forceinline__ void gemm_core(const _Float16* __restrict__ Ap,
                                          const _Float16* __restrict__ Bp,
                                          char* lds, floatx4 (&acc)[4][4]) {
    const int tid  = threadIdx.x;
    const int lane = tid & 63;
    const int wid  = tid >> 6;
    const int wr = wid >> 1, wc = wid & 1;
    const int r16 = lane & 15;
    const int kk  = (lane >> 4) * 8;

    // staging map (round-5 verified): instr i: row += (i&1)*64, ks half = i>>1
    const int srow = tid >> 2, scol = (tid & 3) * 8;
    const _Float16* As0 = Ap + (size_t)srow * DIM + scol;
    const _Float16* Bs0 = Bp + (size_t)srow * DIM + scol;

    auto stage = [&](int buf, int t) {     // t = K-step index (BK=64)
        char* Ad = lds + buf * 32768;
        char* Bd = Ad + 16384;
        int k0 = t * 64;
        #pragma unroll
        for (int i = 0; i < 4; i++) {
            int off = (i & 1) * 64 * DIM + (i >> 1) * 32 + k0;
            gload16(As0 + off, Ad + i * 4096 + wid * 1024);
            gload16(Bs0 + off, Bd + i * 4096 + wid * 1024);
        }
    };

    auto compute = [&](int buf) {
        char* Ad = lds + buf * 32768;
        char* Bd = Ad + 16384;
        #pragma unroll
        for (int ks = 0; ks < 2; ks++) {
            half8 a[4], b[4];
            #pragma unroll
            for (int m = 0; m < 4; m++)
                a[m] = *reinterpret_cast<half8*>(Ad + ks * 8192 + (wr * 64 + m * 16 + r16) * 64 + kk * 2);
            #pragma unroll
            for (int n = 0; n < 4; n++)
                b[n] = *reinterpret_cast<half8*>(Bd + ks * 8192 + (wc * 64 + n * 16 + r16) * 64 + kk * 2);
            #pragma unroll
            for (int m = 0; m < 4; m++)
                #pragma unroll
                for (int n = 0; n < 4; n++)
                    acc[m][n] = __builtin_amdgcn_mfma_f32_16x16x32_f16(a[m], b[n], acc[m][n], 0, 0, 0);
        }
    };

    stage(0, 0);
    stage(1, 1);                               // 16 loads/wave outstanding
    #pragma unroll 1
    for (int t = 0; t < 14; t += 2) {          // steps 0..13; stages 2..15
        VMCNT(8); BAR();                       // buf0 (step t) ready everywhere
        compute(0);
        BAR();                                 // all waves done reading buf0
        stage(0, t + 2);                       // 16 outstanding
        VMCNT(8); BAR();                       // buf1 (step t+1) ready
        compute(1);
        BAR();
        stage(1, t + 3);                       // 16 outstanding
    }
    // steps 14, 15 (peeled; no more staging)
    VMCNT(8); BAR();
    compute(0);
    BAR();
    VMCNT(0); BAR();
    compute(1);
}

// ---------------- 3. fused QKV projections (XCD-swizzled tile ids) ----------------
// z=0: Q = H*Wq^T (scaled, per-head layout)  z=1: K (per-head layout)
// z=2: V^T = Wv^T * H^T  (row-major [1024][2048]), tiles remapped from 16x8 grid
__global__ __launch_bounds__(256) void gemm_qkv(
        const _Float16* __restrict__ Hf, const _Float16* __restrict__ Wt,
        _Float16* __restrict__ Qp, _Float16* __restrict__ Kp, _Float16* __restrict__ Vt) {
    __shared__ char lds[65536];
    floatx4 acc[4][4] = {};

    // XCD-aware chunked remap of the 384 workgroups (384 % 8 == 0 -> bijective)
    int lin = blockIdx.x + 16 * blockIdx.y + 128 * blockIdx.z;   // 0..383
    int swz = (lin & 7) * 48 + (lin >> 3);
    int z  = swz >> 7;            // 0..2
    int rem = swz & 127;
    int bx = rem & 15, by = rem >> 4;    // bx 0..15, by 0..7

    int tm, tn;
    const _Float16 *Ap, *Bp;
    if (z < 2) {
        tm = bx; tn = by;                                       // 16 x 8
        Ap = Hf + (size_t)tm * 128 * DIM;
        Bp = Wt + (size_t)z * DIM * DIM + (size_t)tn * 128 * DIM;
    } else {
        tm = bx & 7; tn = by * 2 + (bx >> 3);                   // 8 x 16
        Ap = Wt + (size_t)2 * DIM * DIM + (size_t)tm * 128 * DIM;
        Bp = Hf + (size_t)tn * 128 * DIM;
    }
    gemm_core(Ap, Bp, lds, acc);

    int lane = threadIdx.x & 63, wid = threadIdx.x >> 6;
    int wr = wid >> 1, wc = wid & 1;
    float qs = (z == 0) ? QSCALE : 1.0f;
    _Float16* Oz = (z == 0) ? Qp : Kp;

    #pragma unroll
    for (int m = 0; m < 4; m++) {
        #pragma unroll
        for (int n = 0; n < 4; n++) {
            #pragma unroll
            for (int r = 0; r < 4; r++) {
                int row = tm * 128 + wr * 64 + m * 16 + (lane >> 4) * 4 + r;
                int col = tn * 128 + wc * 64 + n * 16 + (lane & 15);
                float v = acc[m][n][r];
                if (z < 2) {
                    int head = col >> 6;
                    Oz[(size_t)head * (SEQ * HD) + (size_t)row * HD + (col & 63)] = (_Float16)(v * qs);
                } else {
                    Vt[(size_t)row * SEQ + col] = (_Float16)v;
                }
            }
        }
    }
}

// ---------------- 5. output projection + bias (XCD-swizzled) ----------------
__global__ __launch_bounds__(256) void gemm_o(
        const _Float16* __restrict__ AO, const _Float16* __restrict__ WoT,
        const float* __restrict__ bias, float* __restrict__ out) {
    __shared__ char lds[65536];
    floatx4 acc[4][4] = {};

    int lin = blockIdx.x + 16 * blockIdx.y;      // 0..127
    int swz = (lin & 7) * 16 + (lin >> 3);       // 128 % 8 == 0 -> bijective
    int tm = swz & 15, tn = swz >> 4;            // 16 x 8

    gemm_core(AO + (size_t)tm * 128 * DIM, WoT + (size_t)tn * 128 * DIM, lds, acc);

    int lane = threadIdx.x & 63, wid = threadIdx.x >> 6;
    int wr = wid >> 1, wc = wid & 1;
    #pragma unroll
    for (int m = 0; m < 4; m++) {
        #pragma unroll
        for (int n = 0; n < 4; n++) {
            #pragma unroll
            for (int r = 0; r < 4; r++) {
                int row = tm * 128 + wr * 64 + m * 16 + (lane >> 4) * 4 + r;
                int col = tn * 128 + wc * 64 + n * 16 + (lane & 15);
                out[(size_t)row * DIM + col] = acc[m][n][r] + bias[col];
            }
        }
    }
}

// ---------------- 4. MFMA windowed attention (XCD-swizzled blocks) ----------------
// 1 wave per (head, f, h) row; 16 queries. Keys: 3 f-chunks x 6 h-rows x 16 w = 288.
__global__ __launch_bounds__(256) void attn_mfma(
        const _Float16* __restrict__ Q,    // [16][2048][64] (scaled)
        const _Float16* __restrict__ K,    // [16][2048][64]
        const _Float16* __restrict__ Vt,   // [16][64][2048]
        _Float16* __restrict__ AO) {       // [2048][1024]
    __shared__ char P_lds[4][16 * 640];    // per-wave P[16 q][288 key] f16, XOR-swizzled

    int wid  = threadIdx.x >> 6;
    int lane = threadIdx.x & 63;
    int g    = lane >> 4;      // 0..3
    int ql   = lane & 15;

    int blk  = blockIdx.x;                 // 0..511
    int sblk = (blk & 7) * 64 + (blk >> 3);  // XCD-chunked, bijective (512 % 8 == 0)
    int bid  = sblk * 4 + wid;
    int rid  = bid & 127;      // (f,h)
    int head = bid >> 7;
    int f    = rid >> 4;
    int hq   = rid & 15;
    int s0   = rid << 4;

    const _Float16* Qh = Q  + (size_t)head * (SEQ * HD);
    const _Float16* Kh = K  + (size_t)head * (SEQ * HD);
    const _Float16* Vh = Vt + (size_t)head * (HD * SEQ);

    int f_start = min(max(f - 1, 0), 5);
    int h_start = min(max(hq - 2, 0), 10);

    // per-lane w-mask: key w' = g*4+r, query w = ql
    bool wm[4];
    #pragma unroll
    for (int r = 0; r < 4; r++) {
        int wp = g * 4 + r;
        wm[r] = (wp - ql <= 2) && (ql - wp <= 2);
    }

    // Q B-frags (2 k-steps over d=64)
    half8 qf[2];
    #pragma unroll
    for (int ks = 0; ks < 2; ks++)
        qf[ks] = *reinterpret_cast<const half8*>(Qh + (size_t)(s0 + ql) * HD + ks * 32 + g * 8);

    float lsum = 0.f;
    int swz = (ql & 7) << 4;

    #pragma unroll
    for (int fi = 0; fi < 3; fi++) {
        int fp = f_start + fi;
        bool fok = (fp - f <= 1) && (f - fp <= 1);
        int sbase = fp * 256 + h_start * 16;
        const _Float16* Kc = Kh + (size_t)sbase * HD;

        floatx4 sacc[6];
        #pragma unroll
        for (int j = 0; j < 6; j++) sacc[j] = (floatx4){0.f, 0.f, 0.f, 0.f};

        #pragma unroll
        for (int j = 0; j < 6; j++) {
            #pragma unroll
            for (int ks = 0; ks < 2; ks++) {
                half8 kf = *reinterpret_cast<const half8*>(Kc + (size_t)(j * 16 + ql) * HD + ks * 32 + g * 8);
                sacc[j] = __builtin_amdgcn_mfma_f32_16x16x32_f16(kf, qf[ks], sacc[j], 0, 0, 0);
            }
        }

        #pragma unroll
        for (int j = 0; j < 6; j++) {
            int hp = h_start + j;
            bool ok = fok && (hp - hq <= 2) && (hq - hp <= 2);
            half4 pv;
            #pragma unroll
            for (int r = 0; r < 4; r++) {
                float sv = (ok && wm[r]) ? sacc[j][r] : -10000.f;
                float p  = __builtin_amdgcn_exp2f(sv);
                lsum += p;
                pv[r] = (_Float16)p;
            }
            int byte = (ql * 640 + (fi * 96 + j * 16 + g * 4) * 2) ^ swz;
            *reinterpret_cast<half4*>(&P_lds[wid][byte]) = pv;
        }
    }

    // row sums (q = ql lives in 4 lane-groups)
    lsum += __shfl_xor(lsum, 16);
    lsum += __shfl_xor(lsum, 32);
    float inv = __builtin_amdgcn_rcpf(lsum);

    __syncthreads();

    floatx4 oacc[4];
    #pragma unroll
    for (int dt = 0; dt < 4; dt++) oacc[dt] = (floatx4){0.f, 0.f, 0.f, 0.f};

    #pragma unroll
    for (int fi = 0; fi < 3; fi++) {
        int sbase = (f_start + fi) * 256 + h_start * 16;
        #pragma unroll
        for (int kw = 0; kw < 3; kw++) {
            int kcol = fi * 96 + kw * 32;
            int byte = (ql * 640 + (kcol + g * 8) * 2) ^ swz;
            half8 pa = *reinterpret_cast<half8*>(&P_lds[wid][byte]);
            #pragma unroll
            for (int dt = 0; dt < 4; dt++) {
                half8 vf = *reinterpret_cast<const half8*>(
                    Vh + (size_t)(dt * 16 + ql) * SEQ + sbase + kw * 32 + g * 8);
                oacc[dt] = __builtin_amdgcn_mfma_f32_16x16x32_f16(pa, vf, oacc[dt], 0, 0, 0);
            }
        }
    }

    // epilogue: C row = q = g*4+rr, col = d = dt*16+ql; scale by 1/sum
    #pragma unroll
    for (int rr = 0; rr < 4; rr++) {
        float invr = __shfl(inv, g * 4 + rr);
        #pragma unroll
        for (int dt = 0; dt < 4; dt++) {
            AO[(size_t)(s0 + g * 4 + rr) * DIM + head * HD + dt * 16 + ql] =
                (_Float16)(oacc[dt][rr] * invr);
        }
    }
}

// ---------------- launch ----------------
extern "C" void kernel_launch(void* const* d_in, const int* in_sizes, int n_in,
                              void* d_out, int out_size, void* d_ws, size_t ws_size,
                              hipStream_t stream) {
    const float* H  = (const float*)d_in[0];
    const float* Wq = (const float*)d_in[1];
    const float* Wk = (const float*)d_in[2];
    const float* Wv = (const float*)d_in[3];
    const float* Wo = (const float*)d_in[4];
    const float* bo = (const float*)d_in[5];

    char* ws = (char*)d_ws;
    // layout: Hf16 [0,4M) | Wt x4 [4M,12M) | Q [12M,16M) | K [16M,20M) | Vt [20M,24M) | AO [24M,28M)
    _Float16* Hf = (_Float16*)(ws);
    _Float16* Wt = (_Float16*)(ws + (4u  << 20));
    _Float16* Qp = (_Float16*)(ws + (12u << 20));
    _Float16* Kp = (_Float16*)(ws + (16u << 20));
    _Float16* Vt = (_Float16*)(ws + (20u << 20));
    _Float16* AO = (_Float16*)(ws + (24u << 20));

    // 1+2. H -> f16 and weights -> transposed f16 (vectorized)
    prep<<<dim3(16, 16, 5), 256, 0, stream>>>(H, Hf, Wq, Wk, Wv, Wo, Wt);

    // 3. fused Q, K, V^T projections (z=0,1: QK per-head; z=2: V^T remapped)
    gemm_qkv<<<dim3(16, 8, 3), 256, 0, stream>>>(Hf, Wt, Qp, Kp, Vt);

    // 4. windowed MFMA attention: 2048 one-wave rows, 4 per block
    attn_mfma<<<dim3(NHEAD * 128 / 4), 256, 0, stream>>>(Qp, Kp, Vt, AO);

    // 5. output projection + bias
    gemm_o<<<dim3(16, 8), 256, 0, stream>>>(AO, Wt + (size_t)3 * DIM * DIM, bo, (float*)d_out);
}

// Round 10
// 59.967 us; speedup vs baseline: 1.6321x; 1.1171x over previous
//
#include <hip/hip_runtime.h>
#include <hip/hip_bf16.h>
#include <hip/hip_fp16.h>

// ---------------- constants (problem is fixed-shape) ----------------
#define SEQ   2048
#define DIM   1024
#define NHEAD 16
#define HD    64
// grid (8,16,16), window (3,5,5) -> half windows 1,2,2
#define QSCALE 0.18033688011112042f   // (1/sqrt(64)) * log2(e), folded into Q

typedef _Float16 half8 __attribute__((ext_vector_type(8)));
typedef _Float16 half4 __attribute__((ext_vector_type(4)));
typedef float    floatx4 __attribute__((ext_vector_type(4)));

// async global->LDS, 16B per lane; LDS dest is wave-uniform base + lane*16
__device__ __forceinline__ void gload16(const void* g, void* l) {
    __builtin_amdgcn_global_load_lds(
        (const __attribute__((address_space(1))) unsigned int*)g,
        (__attribute__((address_space(3))) unsigned int*)l, 16, 0, 0);
}

#define VMCNT(n) asm volatile("s_waitcnt vmcnt(" #n ")" ::: "memory")
#define LGKM0()  asm volatile("s_waitcnt lgkmcnt(0)" ::: "memory")
#define BAR()    __builtin_amdgcn_s_barrier()

// ---------------- 1+2 merged prep (vectorized) ----------------
// z<4: 64x64 transpose-cvt tiles through padded LDS (float4 loads, half8 stores)
// z=4: H f32->f16, float4 x2 -> half8, 32 elems/thread
__global__ __launch_bounds__(256) void prep(
        const float* __restrict__ H, _Float16* __restrict__ Hf,
        const float* __restrict__ W0, const float* __restrict__ W1,
        const float* __restrict__ W2, const float* __restrict__ W3,
        _Float16* __restrict__ T) {
    __shared__ float tile[64][65];    // +1 pad: both phases <=2-way bank aliasing
    int z = blockIdx.z;
    int t = threadIdx.x;
    if (z < 4) {
        const float* W = (z == 0) ? W0 : (z == 1) ? W1 : (z == 2) ? W2 : W3;
        _Float16* Tz = T + (size_t)z * (DIM * DIM);
        int bx = blockIdx.x * 64;     // n base
        int by = blockIdx.y * 64;     // k base
        #pragma unroll
        for (int i = 0; i < 4; i++) {
            int id = t + i * 256;
            int r = id >> 4;                  // k_local 0..63
            int c = (id & 15) * 4;            // n_local 0..60
            float4 v = *reinterpret_cast<const float4*>(W + (size_t)(by + r) * DIM + bx + c);
            tile[r][c] = v.x; tile[r][c + 1] = v.y; tile[r][c + 2] = v.z; tile[r][c + 3] = v.w;
        }
        __syncthreads();
        #pragma unroll
        for (int i = 0; i < 2; i++) {
            int id = t + i * 256;
            int nr = id >> 3;                 // n_local 0..63
            int c8 = id & 7;                  // k chunk
            half8 o;
            #pragma unroll
            for (int j = 0; j < 8; j++) o[j] = (_Float16)tile[c8 * 8 + j][nr];
            *reinterpret_cast<half8*>(Tz + (size_t)(bx + nr) * DIM + by + c8 * 8) = o;
        }
    } else {
        int wg = blockIdx.y * 16 + blockIdx.x;   // 0..255
        #pragma unroll
        for (int i = 0; i < 4; i++) {
            int base = ((wg * 4 + i) * 256 + t) * 8;
            float4 v0 = *reinterpret_cast<const float4*>(H + base);
            float4 v1 = *reinterpret_cast<const float4*>(H + base + 4);
            half8 o = { (_Float16)v0.x, (_Float16)v0.y, (_Float16)v0.z, (_Float16)v0.w,
                        (_Float16)v1.x, (_Float16)v1.y, (_Float16)v1.z, (_Float16)v1.w };
            *reinterpret_cast<half8*>(Hf + base) = o;
        }
    }
}

// ---------------- GEMM core A: 128x128 tile, BK=64, 2-deep counted-vmcnt pipeline ----
// (round-9 proven; used by gemm_qkv — untouched)
__device__ __forceinline__ void gemm_core(const _Float16* __restrict__ Ap,
                                          const _Float16* __restrict__ Bp,
                                          char* lds, floatx4 (&acc)[4][4]) {
    const int tid  = threadIdx.x;
    const int lane = tid & 63;
    const int wid  = tid >> 6;
    const int wr = wid >> 1, wc = wid & 1;
    const int r16 = lane & 15;
    const int kk  = (lane >> 4) * 8;

    const int srow = tid >> 2, scol = (tid & 3) * 8;
    const _Float16* As0 = Ap + (size_t)srow * DIM + scol;
    const _Float16* Bs0 = Bp + (size_t)srow * DIM + scol;

    auto stage = [&](int buf, int t) {     // t = K-step index (BK=64)
        char* Ad = lds + buf * 32768;
        char* Bd = Ad + 16384;
        int k0 = t * 64;
        #pragma unroll
        for (int i = 0; i < 4; i++) {
            int off = (i & 1) * 64 * DIM + (i >> 1) * 32 + k0;
            gload16(As0 + off, Ad + i * 4096 + wid * 1024);
            gload16(Bs0 + off, Bd + i * 4096 + wid * 1024);
        }
    };

    auto compute = [&](int buf) {
        char* Ad = lds + buf * 32768;
        char* Bd = Ad + 16384;
        #pragma unroll
        for (int ks = 0; ks < 2; ks++) {
            half8 a[4], b[4];
            #pragma unroll
            for (int m = 0; m < 4; m++)
                a[m] = *reinterpret_cast<half8*>(Ad + ks * 8192 + (wr * 64 + m * 16 + r16) * 64 + kk * 2);
            #pragma unroll
            for (int n = 0; n < 4; n++)
                b[n] = *reinterpret_cast<half8*>(Bd + ks * 8192 + (wc * 64 + n * 16 + r16) * 64 + kk * 2);
            #pragma unroll
            for (int m = 0; m < 4; m++)
                #pragma unroll
                for (int n = 0; n < 4; n++)
                    acc[m][n] = __builtin_amdgcn_mfma_f32_16x16x32_f16(a[m], b[n], acc[m][n], 0, 0, 0);
        }
    };

    stage(0, 0);
    stage(1, 1);                               // 16 loads/wave outstanding
    #pragma unroll 1
    for (int t = 0; t < 14; t += 2) {
        VMCNT(8); BAR();
        compute(0);
        BAR();
        stage(0, t + 2);
        VMCNT(8); BAR();
        compute(1);
        BAR();
        stage(1, t + 3);
    }
    VMCNT(8); BAR();
    compute(0);
    BAR();
    VMCNT(0); BAR();
    compute(1);
}

// ---------------- GEMM core B: 128x64 tile, BK=64, same pipeline (for gemm_o) ------
// 4 waves (2x2), wave tile 64x32 = 4x2 frags. LDS/buffer: A 16KB + B 8KB = 24KB;
// 2 buffers = 48KB. 6 loads/wave/step -> vmcnt(6) = older buffer complete.
__device__ __forceinline__ void gemm_core64(const _Float16* __restrict__ Ap,
                                            const _Float16* __restrict__ Bp,
                                            char* lds, floatx4 (&acc)[4][2]) {
    const int tid  = threadIdx.x;
    const int lane = tid & 63;
    const int wid  = tid >> 6;
    const int wr = wid >> 1, wc = wid & 1;
    const int r16 = lane & 15;
    const int kk  = (lane >> 4) * 8;

    const int srow = tid >> 2, scol = (tid & 3) * 8;
    const _Float16* As0 = Ap + (size_t)srow * DIM + scol;   // rows 0..63 (+64 via i&1)
    const _Float16* Bs0 = Bp + (size_t)srow * DIM + scol;   // rows 0..63

    auto stage = [&](int buf, int t) {
        char* Ad = lds + buf * 24576;
        char* Bd = Ad + 16384;
        int k0 = t * 64;
        #pragma unroll
        for (int i = 0; i < 4; i++) {        // A: two row-halves x two ks-halves
            int off = (i & 1) * 64 * DIM + (i >> 1) * 32 + k0;
            gload16(As0 + off, Ad + i * 4096 + wid * 1024);
        }
        #pragma unroll
        for (int j = 0; j < 2; j++)          // B: 64 rows, ks-half j
            gload16(Bs0 + j * 32 + k0, Bd + j * 4096 + wid * 1024);
    };

    auto compute = [&](int buf) {
        char* Ad = lds + buf * 24576;
        char* Bd = Ad + 16384;
        #pragma unroll
        for (int ks = 0; ks < 2; ks++) {
            half8 a[4], b[2];
            #pragma unroll
            for (int m = 0; m < 4; m++)
                a[m] = *reinterpret_cast<half8*>(Ad + ks * 8192 + (wr * 64 + m * 16 + r16) * 64 + kk * 2);
            #pragma unroll
            for (int n = 0; n < 2; n++)
                b[n] = *reinterpret_cast<half8*>(Bd + ks * 4096 + (wc * 32 + n * 16 + r16) * 64 + kk * 2);
            #pragma unroll
            for (int m = 0; m < 4; m++)
                #pragma unroll
                for (int n = 0; n < 2; n++)
                    acc[m][n] = __builtin_amdgcn_mfma_f32_16x16x32_f16(a[m], b[n], acc[m][n], 0, 0, 0);
        }
    };

    stage(0, 0);
    stage(1, 1);                               // 12 loads/wave outstanding
    #pragma unroll 1
    for (int t = 0; t < 14; t += 2) {
        VMCNT(6); BAR();
        compute(0);
        BAR();
        stage(0, t + 2);
        VMCNT(6); BAR();
        compute(1);
        BAR();
        stage(1, t + 3);
    }
    VMCNT(6); BAR();
    compute(0);
    BAR();
    VMCNT(0); BAR();
    compute(1);
}

// ---------------- 3. fused QKV projections (XCD-swizzled tile ids) ----------------
__global__ __launch_bounds__(256) void gemm_qkv(
        const _Float16* __restrict__ Hf, const _Float16* __restrict__ Wt,
        _Float16* __restrict__ Qp, _Float16* __restrict__ Kp, _Float16* __restrict__ Vt) {
    __shared__ char lds[65536];
    floatx4 acc[4][4] = {};

    int lin = blockIdx.x + 16 * blockIdx.y + 128 * blockIdx.z;   // 0..383
    int swz = (lin & 7) * 48 + (lin >> 3);
    int z  = swz >> 7;            // 0..2
    int rem = swz & 127;
    int bx = rem & 15, by = rem >> 4;    // bx 0..15, by 0..7

    int tm, tn;
    const _Float16 *Ap, *Bp;
    if (z < 2) {
        tm = bx; tn = by;                                       // 16 x 8
        Ap = Hf + (size_t)tm * 128 * DIM;
        Bp = Wt + (size_t)z * DIM * DIM + (size_t)tn * 128 * DIM;
    } else {
        tm = bx & 7; tn = by * 2 + (bx >> 3);                   // 8 x 16
        Ap = Wt + (size_t)2 * DIM * DIM + (size_t)tm * 128 * DIM;
        Bp = Hf + (size_t)tn * 128 * DIM;
    }
    gemm_core(Ap, Bp, lds, acc);

    int lane = threadIdx.x & 63, wid = threadIdx.x >> 6;
    int wr = wid >> 1, wc = wid & 1;
    float qs = (z == 0) ? QSCALE : 1.0f;
    _Float16* Oz = (z == 0) ? Qp : Kp;

    #pragma unroll
    for (int m = 0; m < 4; m++) {
        #pragma unroll
        for (int n = 0; n < 4; n++) {
            #pragma unroll
            for (int r = 0; r < 4; r++) {
                int row = tm * 128 + wr * 64 + m * 16 + (lane >> 4) * 4 + r;
                int col = tn * 128 + wc * 64 + n * 16 + (lane & 15);
                float v = acc[m][n][r];
                if (z < 2) {
                    int head = col >> 6;
                    Oz[(size_t)head * (SEQ * HD) + (size_t)row * HD + (col & 63)] = (_Float16)(v * qs);
                } else {
                    Vt[(size_t)row * SEQ + col] = (_Float16)v;
                }
            }
        }
    }
}

// ---------------- 5. output projection + bias: 128x64 tiles, 256 WGs = 1/CU -------
__global__ __launch_bounds__(256) void gemm_o(
        const _Float16* __restrict__ AO, const _Float16* __restrict__ WoT,
        const float* __restrict__ bias, float* __restrict__ out) {
    __shared__ char lds[49152];
    floatx4 acc[4][2] = {};

    int lin = blockIdx.x + 16 * blockIdx.y;      // 0..255
    int swz = (lin & 7) * 32 + (lin >> 3);       // 256 % 8 == 0 -> bijective
    int tm = swz & 15, tn = swz >> 4;            // 16 x 16

    gemm_core64(AO + (size_t)tm * 128 * DIM, WoT + (size_t)tn * 64 * DIM, lds, acc);

    int lane = threadIdx.x & 63, wid = threadIdx.x >> 6;
    int wr = wid >> 1, wc = wid & 1;
    #pragma unroll
    for (int m = 0; m < 4; m++) {
        #pragma unroll
        for (int n = 0; n < 2; n++) {
            #pragma unroll
            for (int r = 0; r < 4; r++) {
                int row = tm * 128 + wr * 64 + m * 16 + (lane >> 4) * 4 + r;
                int col = tn * 64 + wc * 32 + n * 16 + (lane & 15);
                out[(size_t)row * DIM + col] = acc[m][n][r] + bias[col];
            }
        }
    }
}

// ---------------- 4. MFMA windowed attention (XCD-swizzled blocks) ----------------
// 1 wave per (head, f, h) row; 16 queries. Keys: 3 f-chunks x 6 h-rows x 16 w = 288.
// P_lds is WAVE-PRIVATE -> no __syncthreads needed; per-wave lgkmcnt(0) fence only.
// s_setprio(1) around MFMA clusters (T5; m191 regime: independent waves).
__global__ __launch_bounds__(256) void attn_mfma(
        const _Float16* __restrict__ Q,    // [16][2048][64] (scaled)
        const _Float16* __restrict__ K,    // [16][2048][64]
        const _Float16* __restrict__ Vt,   // [16][64][2048]
        _Float16* __restrict__ AO) {       // [2048][1024]
    __shared__ char P_lds[4][16 * 640];    // per-wave P[16 q][288 key] f16, XOR-swizzled

    int wid  = threadIdx.x >> 6;
    int lane = threadIdx.x & 63;
    int g    = lane >> 4;      // 0..3
    int ql   = lane & 15;

    int blk  = blockIdx.x;                 // 0..511
    int sblk = (blk & 7) * 64 + (blk >> 3);  // XCD-chunked, bijective (512 % 8 == 0)
    int bid  = sblk * 4 + wid;
    int rid  = bid & 127;      // (f,h)
    int head = bid >> 7;
    int f    = rid >> 4;
    int hq   = rid & 15;
    int s0   = rid << 4;

    const _Float16* Qh = Q  + (size_t)head * (SEQ * HD);
    const _Float16* Kh = K  + (size_t)head * (SEQ * HD);
    const _Float16* Vh = Vt + (size_t)head * (HD * SEQ);

    int f_start = min(max(f - 1, 0), 5);
    int h_start = min(max(hq - 2, 0), 10);

    // per-lane w-mask: key w' = g*4+r, query w = ql
    bool wm[4];
    #pragma unroll
    for (int r = 0; r < 4; r++) {
        int wp = g * 4 + r;
        wm[r] = (wp - ql <= 2) && (ql - wp <= 2);
    }

    // Q B-frags (2 k-steps over d=64)
    half8 qf[2];
    #pragma unroll
    for (int ks = 0; ks < 2; ks++)
        qf[ks] = *reinterpret_cast<const half8*>(Qh + (size_t)(s0 + ql) * HD + ks * 32 + g * 8);

    float lsum = 0.f;
    int swz = (ql & 7) << 4;

    #pragma unroll
    for (int fi = 0; fi < 3; fi++) {
        int fp = f_start + fi;
        bool fok = (fp - f <= 1) && (f - fp <= 1);
        int sbase = fp * 256 + h_start * 16;
        const _Float16* Kc = Kh + (size_t)sbase * HD;

        floatx4 sacc[6];
        #pragma unroll
        for (int j = 0; j < 6; j++) sacc[j] = (floatx4){0.f, 0.f, 0.f, 0.f};

        __builtin_amdgcn_s_setprio(1);
        #pragma unroll
        for (int j = 0; j < 6; j++) {
            #pragma unroll
            for (int ks = 0; ks < 2; ks++) {
                half8 kf = *reinterpret_cast<const half8*>(Kc + (size_t)(j * 16 + ql) * HD + ks * 32 + g * 8);
                sacc[j] = __builtin_amdgcn_mfma_f32_16x16x32_f16(kf, qf[ks], sacc[j], 0, 0, 0);
            }
        }
        __builtin_amdgcn_s_setprio(0);

        #pragma unroll
        for (int j = 0; j < 6; j++) {
            int hp = h_start + j;
            bool ok = fok && (hp - hq <= 2) && (hq - hp <= 2);
            half4 pv;
            #pragma unroll
            for (int r = 0; r < 4; r++) {
                float sv = (ok && wm[r]) ? sacc[j][r] : -10000.f;
                float p  = __builtin_amdgcn_exp2f(sv);
                lsum += p;
                pv[r] = (_Float16)p;
            }
            int byte = (ql * 640 + (fi * 96 + j * 16 + g * 4) * 2) ^ swz;
            *reinterpret_cast<half4*>(&P_lds[wid][byte]) = pv;
        }
    }

    // row sums (q = ql lives in 4 lane-groups)
    lsum += __shfl_xor(lsum, 16);
    lsum += __shfl_xor(lsum, 32);
    float inv = __builtin_amdgcn_rcpf(lsum);

    LGKM0();   // wave-private P_lds: own ds_writes retired; no cross-wave barrier needed

    floatx4 oacc[4];
    #pragma unroll
    for (int dt = 0; dt < 4; dt++) oacc[dt] = (floatx4){0.f, 0.f, 0.f, 0.f};

    #pragma unroll
    for (int fi = 0; fi < 3; fi++) {
        int sbase = (f_start + fi) * 256 + h_start * 16;
        __builtin_amdgcn_s_setprio(1);
        #pragma unroll
        for (int kw = 0; kw < 3; kw++) {
            int kcol = fi * 96 + kw * 32;
            int byte = (ql * 640 + (kcol + g * 8) * 2) ^ swz;
            half8 pa = *reinterpret_cast<half8*>(&P_lds[wid][byte]);
            #pragma unroll
            for (int dt = 0; dt < 4; dt++) {
                half8 vf = *reinterpret_cast<const half8*>(
                    Vh + (size_t)(dt * 16 + ql) * SEQ + sbase + kw * 32 + g * 8);
                oacc[dt] = __builtin_amdgcn_mfma_f32_16x16x32_f16(pa, vf, oacc[dt], 0, 0, 0);
            }
        }
        __builtin_amdgcn_s_setprio(0);
    }

    // epilogue: C row = q = g*4+rr, col = d = dt*16+ql; scale by 1/sum
    #pragma unroll
    for (int rr = 0; rr < 4; rr++) {
        float invr = __shfl(inv, g * 4 + rr);
        #pragma unroll
        for (int dt = 0; dt < 4; dt++) {
            AO[(size_t)(s0 + g * 4 + rr) * DIM + head * HD + dt * 16 + ql] =
                (_Float16)(oacc[dt][rr] * invr);
        }
    }
}

// ---------------- launch ----------------
extern "C" void kernel_launch(void* const* d_in, const int* in_sizes, int n_in,
                              void* d_out, int out_size, void* d_ws, size_t ws_size,
                              hipStream_t stream) {
    const float* H  = (const float*)d_in[0];
    const float* Wq = (const float*)d_in[1];
    const float* Wk = (const float*)d_in[2];
    const float* Wv = (const float*)d_in[3];
    const float* Wo = (const float*)d_in[4];
    const float* bo = (const float*)d_in[5];

    char* ws = (char*)d_ws;
    // layout: Hf16 [0,4M) | Wt x4 [4M,12M) | Q [12M,16M) | K [16M,20M) | Vt [20M,24M) | AO [24M,28M)
    _Float16* Hf = (_Float16*)(ws);
    _Float16* Wt = (_Float16*)(ws + (4u  << 20));
    _Float16* Qp = (_Float16*)(ws + (12u << 20));
    _Float16* Kp = (_Float16*)(ws + (16u << 20));
    _Float16* Vt = (_Float16*)(ws + (20u << 20));
    _Float16* AO = (_Float16*)(ws + (24u << 20));

    // 1+2. H -> f16 and weights -> transposed f16 (vectorized)
    prep<<<dim3(16, 16, 5), 256, 0, stream>>>(H, Hf, Wq, Wk, Wv, Wo, Wt);

    // 3. fused Q, K, V^T projections (z=0,1: QK per-head; z=2: V^T remapped)
    gemm_qkv<<<dim3(16, 8, 3), 256, 0, stream>>>(Hf, Wt, Qp, Kp, Vt);

    // 4. windowed MFMA attention: 2048 one-wave rows, 4 per block
    attn_mfma<<<dim3(NHEAD * 128 / 4), 256, 0, stream>>>(Qp, Kp, Vt, AO);

    // 5. output projection + bias: 256 WGs = 1 block/CU (was 128 = half idle)
    gemm_o<<<dim3(16, 16), 256, 0, stream>>>(AO, Wt + (size_t)3 * DIM * DIM, bo, (float*)d_out);
}

// Round 11
// 59.894 us; speedup vs baseline: 1.6340x; 1.0012x over previous
//
#include <hip/hip_runtime.h>
#include <hip/hip_bf16.h>
#include <hip/hip_fp16.h>

// ---------------- constants (problem is fixed-shape) ----------------
#define SEQ   2048
#define DIM   1024
#define NHEAD 16
#define HD    64
// grid (8,16,16), window (3,5,5) -> half windows 1,2,2
#define QSCALE 0.18033688011112042f   // (1/sqrt(64)) * log2(e), folded into Q

typedef _Float16 half8 __attribute__((ext_vector_type(8)));
typedef _Float16 half4 __attribute__((ext_vector_type(4)));
typedef float    floatx4 __attribute__((ext_vector_type(4)));

// async global->LDS, 16B per lane; LDS dest is wave-uniform base + lane*16
__device__ __forceinline__ void gload16(const void* g, void* l) {
    __builtin_amdgcn_global_load_lds(
        (const __attribute__((address_space(1))) unsigned int*)g,
        (__attribute__((address_space(3))) unsigned int*)l, 16, 0, 0);
}

#define VMCNT(n) asm volatile("s_waitcnt vmcnt(" #n ")" ::: "memory")
#define LGKM0()  asm volatile("s_waitcnt lgkmcnt(0)" ::: "memory")
#define BAR()    __builtin_amdgcn_s_barrier()

// ---------------- 1+2 merged prep (vectorized) ----------------
// z<4: 64x64 transpose-cvt tiles through padded LDS (float4 loads, half8 stores)
// z=4: H f32->f16, float4 x2 -> half8, 32 elems/thread
__global__ __launch_bounds__(256) void prep(
        const float* __restrict__ H, _Float16* __restrict__ Hf,
        const float* __restrict__ W0, const float* __restrict__ W1,
        const float* __restrict__ W2, const float* __restrict__ W3,
        _Float16* __restrict__ T) {
    __shared__ float tile[64][65];    // +1 pad: both phases <=2-way bank aliasing
    int z = blockIdx.z;
    int t = threadIdx.x;
    if (z < 4) {
        const float* W = (z == 0) ? W0 : (z == 1) ? W1 : (z == 2) ? W2 : W3;
        _Float16* Tz = T + (size_t)z * (DIM * DIM);
        int bx = blockIdx.x * 64;     // n base
        int by = blockIdx.y * 64;     // k base
        #pragma unroll
        for (int i = 0; i < 4; i++) {
            int id = t + i * 256;
            int r = id >> 4;                  // k_local 0..63
            int c = (id & 15) * 4;            // n_local 0..60
            float4 v = *reinterpret_cast<const float4*>(W + (size_t)(by + r) * DIM + bx + c);
            tile[r][c] = v.x; tile[r][c + 1] = v.y; tile[r][c + 2] = v.z; tile[r][c + 3] = v.w;
        }
        __syncthreads();
        #pragma unroll
        for (int i = 0; i < 2; i++) {
            int id = t + i * 256;
            int nr = id >> 3;                 // n_local 0..63
            int c8 = id & 7;                  // k chunk
            half8 o;
            #pragma unroll
            for (int j = 0; j < 8; j++) o[j] = (_Float16)tile[c8 * 8 + j][nr];
            *reinterpret_cast<half8*>(Tz + (size_t)(bx + nr) * DIM + by + c8 * 8) = o;
        }
    } else {
        int wg = blockIdx.y * 16 + blockIdx.x;   // 0..255
        #pragma unroll
        for (int i = 0; i < 4; i++) {
            int base = ((wg * 4 + i) * 256 + t) * 8;
            float4 v0 = *reinterpret_cast<const float4*>(H + base);
            float4 v1 = *reinterpret_cast<const float4*>(H + base + 4);
            half8 o = { (_Float16)v0.x, (_Float16)v0.y, (_Float16)v0.z, (_Float16)v0.w,
                        (_Float16)v1.x, (_Float16)v1.y, (_Float16)v1.z, (_Float16)v1.w };
            *reinterpret_cast<half8*>(Hf + base) = o;
        }
    }
}

// ---------------- GEMM core: 128x64 tile, BK=64, 2-deep counted-vmcnt pipeline ----
// 4 waves (2x2), wave tile 64x32 = 4x2 frags of mfma_f32_16x16x32_f16.
// LDS/buffer: A 16KB + B 8KB = 24KB; 2 buffers = 48KB (2 blocks/CU co-resident).
// 6 loads/wave/step -> vmcnt(6) = older buffer complete; never 0 in main loop.
__device__ __forceinline__ void gemm_core64(const _Float16* __restrict__ Ap,
                                            const _Float16* __restrict__ Bp,
                                            char* lds, floatx4 (&acc)[4][2]) {
    const int tid  = threadIdx.x;
    const int lane = tid & 63;
    const int wid  = tid >> 6;
    const int wr = wid >> 1, wc = wid & 1;
    const int r16 = lane & 15;
    const int kk  = (lane >> 4) * 8;

    const int srow = tid >> 2, scol = (tid & 3) * 8;
    const _Float16* As0 = Ap + (size_t)srow * DIM + scol;   // rows 0..63 (+64 via i&1)
    const _Float16* Bs0 = Bp + (size_t)srow * DIM + scol;   // rows 0..63

    auto stage = [&](int buf, int t) {
        char* Ad = lds + buf * 24576;
        char* Bd = Ad + 16384;
        int k0 = t * 64;
        #pragma unroll
        for (int i = 0; i < 4; i++) {        // A: two row-halves x two ks-halves
            int off = (i & 1) * 64 * DIM + (i >> 1) * 32 + k0;
            gload16(As0 + off, Ad + i * 4096 + wid * 1024);
        }
        #pragma unroll
        for (int j = 0; j < 2; j++)          // B: 64 rows, ks-half j
            gload16(Bs0 + j * 32 + k0, Bd + j * 4096 + wid * 1024);
    };

    auto compute = [&](int buf) {
        char* Ad = lds + buf * 24576;
        char* Bd = Ad + 16384;
        #pragma unroll
        for (int ks = 0; ks < 2; ks++) {
            half8 a[4], b[2];
            #pragma unroll
            for (int m = 0; m < 4; m++)
                a[m] = *reinterpret_cast<half8*>(Ad + ks * 8192 + (wr * 64 + m * 16 + r16) * 64 + kk * 2);
            #pragma unroll
            for (int n = 0; n < 2; n++)
                b[n] = *reinterpret_cast<half8*>(Bd + ks * 4096 + (wc * 32 + n * 16 + r16) * 64 + kk * 2);
            #pragma unroll
            for (int m = 0; m < 4; m++)
                #pragma unroll
                for (int n = 0; n < 2; n++)
                    acc[m][n] = __builtin_amdgcn_mfma_f32_16x16x32_f16(a[m], b[n], acc[m][n], 0, 0, 0);
        }
    };

    stage(0, 0);
    stage(1, 1);                               // 12 loads/wave outstanding
    #pragma unroll 1
    for (int t = 0; t < 14; t += 2) {
        VMCNT(6); BAR();
        compute(0);
        BAR();
        stage(0, t + 2);
        VMCNT(6); BAR();
        compute(1);
        BAR();
        stage(1, t + 3);
    }
    VMCNT(6); BAR();
    compute(0);
    BAR();
    VMCNT(0); BAR();
    compute(1);
}

// ---------------- 3. fused QKV projections: 128x64 tiles, 768 WGs = 3/CU ----------
// z=0: Q = H*Wq^T (scaled, per-head layout)  z=1: K (per-head layout)
// z=2: V^T = Wv^T * H^T  (row-major [1024][2048])
__global__ __launch_bounds__(256) void gemm_qkv(
        const _Float16* __restrict__ Hf, const _Float16* __restrict__ Wt,
        _Float16* __restrict__ Qp, _Float16* __restrict__ Kp, _Float16* __restrict__ Vt) {
    __shared__ char lds[49152];
    floatx4 acc[4][2] = {};

    // XCD-aware chunked remap of 768 workgroups (768 % 8 == 0 -> bijective):
    // each XCD gets 96 consecutive tiles
    int lin = blockIdx.x + 256 * blockIdx.z;     // 0..767 (x: 0..255, z: 0..2)
    int swz = (lin & 7) * 96 + (lin >> 3);
    int z   = swz >> 8;            // 0..2
    int rem = swz & 255;

    int tm, tn;
    const _Float16 *Ap, *Bp;
    if (z < 2) {
        tm = rem & 15; tn = rem >> 4;                           // 16 m x 16 n
        Ap = Hf + (size_t)tm * 128 * DIM;
        Bp = Wt + (size_t)z * DIM * DIM + (size_t)tn * 64 * DIM;
    } else {
        tm = rem & 7; tn = rem >> 3;                            // 8 m x 32 n
        Ap = Wt + (size_t)2 * DIM * DIM + (size_t)tm * 128 * DIM;
        Bp = Hf + (size_t)tn * 64 * DIM;
    }
    gemm_core64(Ap, Bp, lds, acc);

    int lane = threadIdx.x & 63, wid = threadIdx.x >> 6;
    int wr = wid >> 1, wc = wid & 1;
    float qs = (z == 0) ? QSCALE : 1.0f;
    _Float16* Oz = (z == 0) ? Qp : Kp;

    #pragma unroll
    for (int m = 0; m < 4; m++) {
        #pragma unroll
        for (int n = 0; n < 2; n++) {
            #pragma unroll
            for (int r = 0; r < 4; r++) {
                int row = tm * 128 + wr * 64 + m * 16 + (lane >> 4) * 4 + r;
                int col = tn * 64 + wc * 32 + n * 16 + (lane & 15);
                float v = acc[m][n][r];
                if (z < 2) {
                    int head = col >> 6;       // == tn
                    Oz[(size_t)head * (SEQ * HD) + (size_t)row * HD + (col & 63)] = (_Float16)(v * qs);
                } else {
                    Vt[(size_t)row * SEQ + col] = (_Float16)v;
                }
            }
        }
    }
}

// ---------------- 5. output projection + bias: 128x64 tiles, 256 WGs = 1/CU -------
__global__ __launch_bounds__(256) void gemm_o(
        const _Float16* __restrict__ AO, const _Float16* __restrict__ WoT,
        const float* __restrict__ bias, float* __restrict__ out) {
    __shared__ char lds[49152];
    floatx4 acc[4][2] = {};

    int lin = blockIdx.x + 16 * blockIdx.y;      // 0..255
    int swz = (lin & 7) * 32 + (lin >> 3);       // 256 % 8 == 0 -> bijective
    int tm = swz & 15, tn = swz >> 4;            // 16 x 16

    gemm_core64(AO + (size_t)tm * 128 * DIM, WoT + (size_t)tn * 64 * DIM, lds, acc);

    int lane = threadIdx.x & 63, wid = threadIdx.x >> 6;
    int wr = wid >> 1, wc = wid & 1;
    #pragma unroll
    for (int m = 0; m < 4; m++) {
        #pragma unroll
        for (int n = 0; n < 2; n++) {
            #pragma unroll
            for (int r = 0; r < 4; r++) {
                int row = tm * 128 + wr * 64 + m * 16 + (lane >> 4) * 4 + r;
                int col = tn * 64 + wc * 32 + n * 16 + (lane & 15);
                out[(size_t)row * DIM + col] = acc[m][n][r] + bias[col];
            }
        }
    }
}

// ---------------- 4. MFMA windowed attention (XCD-swizzled blocks) ----------------
// 1 wave per (head, f, h) row; 16 queries. Keys: 3 f-chunks x 6 h-rows x 16 w = 288.
// P_lds is WAVE-PRIVATE -> no __syncthreads needed; per-wave lgkmcnt(0) fence only.
// s_setprio(1) around MFMA clusters (T5; m191 regime: independent waves).
__global__ __launch_bounds__(256) void attn_mfma(
        const _Float16* __restrict__ Q,    // [16][2048][64] (scaled)
        const _Float16* __restrict__ K,    // [16][2048][64]
        const _Float16* __restrict__ Vt,   // [16][64][2048]
        _Float16* __restrict__ AO) {       // [2048][1024]
    __shared__ char P_lds[4][16 * 640];    // per-wave P[16 q][288 key] f16, XOR-swizzled

    int wid  = threadIdx.x >> 6;
    int lane = threadIdx.x & 63;
    int g    = lane >> 4;      // 0..3
    int ql   = lane & 15;

    int blk  = blockIdx.x;                 // 0..511
    int sblk = (blk & 7) * 64 + (blk >> 3);  // XCD-chunked, bijective (512 % 8 == 0)
    int bid  = sblk * 4 + wid;
    int rid  = bid & 127;      // (f,h)
    int head = bid >> 7;
    int f    = rid >> 4;
    int hq   = rid & 15;
    int s0   = rid << 4;

    const _Float16* Qh = Q  + (size_t)head * (SEQ * HD);
    const _Float16* Kh = K  + (size_t)head * (SEQ * HD);
    const _Float16* Vh = Vt + (size_t)head * (HD * SEQ);

    int f_start = min(max(f - 1, 0), 5);
    int h_start = min(max(hq - 2, 0), 10);

    // per-lane w-mask: key w' = g*4+r, query w = ql
    bool wm[4];
    #pragma unroll
    for (int r = 0; r < 4; r++) {
        int wp = g * 4 + r;
        wm[r] = (wp - ql <= 2) && (ql - wp <= 2);
    }

    // Q B-frags (2 k-steps over d=64)
    half8 qf[2];
    #pragma unroll
    for (int ks = 0; ks < 2; ks++)
        qf[ks] = *reinterpret_cast<const half8*>(Qh + (size_t)(s0 + ql) * HD + ks * 32 + g * 8);

    float lsum = 0.f;
    int swz = (ql & 7) << 4;

    #pragma unroll
    for (int fi = 0; fi < 3; fi++) {
        int fp = f_start + fi;
        bool fok = (fp - f <= 1) && (f - fp <= 1);
        int sbase = fp * 256 + h_start * 16;
        const _Float16* Kc = Kh + (size_t)sbase * HD;

        floatx4 sacc[6];
        #pragma unroll
        for (int j = 0; j < 6; j++) sacc[j] = (floatx4){0.f, 0.f, 0.f, 0.f};

        __builtin_amdgcn_s_setprio(1);
        #pragma unroll
        for (int j = 0; j < 6; j++) {
            #pragma unroll
            for (int ks = 0; ks < 2; ks++) {
                half8 kf = *reinterpret_cast<const half8*>(Kc + (size_t)(j * 16 + ql) * HD + ks * 32 + g * 8);
                sacc[j] = __builtin_amdgcn_mfma_f32_16x16x32_f16(kf, qf[ks], sacc[j], 0, 0, 0);
            }
        }
        __builtin_amdgcn_s_setprio(0);

        #pragma unroll
        for (int j = 0; j < 6; j++) {
            int hp = h_start + j;
            bool ok = fok && (hp - hq <= 2) && (hq - hp <= 2);
            half4 pv;
            #pragma unroll
            for (int r = 0; r < 4; r++) {
                float sv = (ok && wm[r]) ? sacc[j][r] : -10000.f;
                float p  = __builtin_amdgcn_exp2f(sv);
                lsum += p;
                pv[r] = (_Float16)p;
            }
            int byte = (ql * 640 + (fi * 96 + j * 16 + g * 4) * 2) ^ swz;
            *reinterpret_cast<half4*>(&P_lds[wid][byte]) = pv;
        }
    }

    // row sums (q = ql lives in 4 lane-groups)
    lsum += __shfl_xor(lsum, 16);
    lsum += __shfl_xor(lsum, 32);
    float inv = __builtin_amdgcn_rcpf(lsum);

    LGKM0();   // wave-private P_lds: own ds_writes retired; no cross-wave barrier needed

    floatx4 oacc[4];
    #pragma unroll
    for (int dt = 0; dt < 4; dt++) oacc[dt] = (floatx4){0.f, 0.f, 0.f, 0.f};

    #pragma unroll
    for (int fi = 0; fi < 3; fi++) {
        int sbase = (f_start + fi) * 256 + h_start * 16;
        __builtin_amdgcn_s_setprio(1);
        #pragma unroll
        for (int kw = 0; kw < 3; kw++) {
            int kcol = fi * 96 + kw * 32;
            int byte = (ql * 640 + (kcol + g * 8) * 2) ^ swz;
            half8 pa = *reinterpret_cast<half8*>(&P_lds[wid][byte]);
            #pragma unroll
            for (int dt = 0; dt < 4; dt++) {
                half8 vf = *reinterpret_cast<const half8*>(
                    Vh + (size_t)(dt * 16 + ql) * SEQ + sbase + kw * 32 + g * 8);
                oacc[dt] = __builtin_amdgcn_mfma_f32_16x16x32_f16(pa, vf, oacc[dt], 0, 0, 0);
            }
        }
        __builtin_amdgcn_s_setprio(0);
    }

    // epilogue: C row = q = g*4+rr, col = d = dt*16+ql; scale by 1/sum
    #pragma unroll
    for (int rr = 0; rr < 4; rr++) {
        float invr = __shfl(inv, g * 4 + rr);
        #pragma unroll
        for (int dt = 0; dt < 4; dt++) {
            AO[(size_t)(s0 + g * 4 + rr) * DIM + head * HD + dt * 16 + ql] =
                (_Float16)(oacc[dt][rr] * invr);
        }
    }
}

// ---------------- launch ----------------
extern "C" void kernel_launch(void* const* d_in, const int* in_sizes, int n_in,
                              void* d_out, int out_size, void* d_ws, size_t ws_size,
                              hipStream_t stream) {
    const float* H  = (const float*)d_in[0];
    const float* Wq = (const float*)d_in[1];
    const float* Wk = (const float*)d_in[2];
    const float* Wv = (const float*)d_in[3];
    const float* Wo = (const float*)d_in[4];
    const float* bo = (const float*)d_in[5];

    char* ws = (char*)d_ws;
    // layout: Hf16 [0,4M) | Wt x4 [4M,12M) | Q [12M,16M) | K [16M,20M) | Vt [20M,24M) | AO [24M,28M)
    _Float16* Hf = (_Float16*)(ws);
    _Float16* Wt = (_Float16*)(ws + (4u  << 20));
    _Float16* Qp = (_Float16*)(ws + (12u << 20));
    _Float16* Kp = (_Float16*)(ws + (16u << 20));
    _Float16* Vt = (_Float16*)(ws + (20u << 20));
    _Float16* AO = (_Float16*)(ws + (24u << 20));

    // 1+2. H -> f16 and weights -> transposed f16 (vectorized)
    prep<<<dim3(16, 16, 5), 256, 0, stream>>>(H, Hf, Wq, Wk, Wv, Wo, Wt);

    // 3. fused Q, K, V^T projections: 128x64 tiles, 768 WGs = exactly 3/CU
    gemm_qkv<<<dim3(256, 1, 3), 256, 0, stream>>>(Hf, Wt, Qp, Kp, Vt);

    // 4. windowed MFMA attention: 2048 one-wave rows, 4 per block
    attn_mfma<<<dim3(NHEAD * 128 / 4), 256, 0, stream>>>(Qp, Kp, Vt, AO);

    // 5. output projection + bias: 256 WGs = 1 block/CU
    gemm_o<<<dim3(16, 16), 256, 0, stream>>>(AO, Wt + (size_t)3 * DIM * DIM, bo, (float*)d_out);
}